// Round 1
// baseline (3642.192 us; speedup 1.0000x reference)
//
#include <hip/hip_runtime.h>
#include <math.h>

#define HH 200
#define WW 200
#define HWP 40000
#define BB 4

__device__ __forceinline__ float gelu_f(float x) {
    return 0.5f * x * (1.0f + erff(x * 0.7071067811865475f));
}

// ---------------- LayerNorm over 64 channels ----------------
__global__ __launch_bounds__(256) void ln_kernel(
    const float* __restrict__ in, const float* __restrict__ w,
    const float* __restrict__ b, float* __restrict__ out)
{
    int p = blockIdx.x * 256 + threadIdx.x;
    int bb = blockIdx.y;
    if (p >= HWP) return;
    const float* ib = in + (size_t)bb * 64 * HWP + p;
    float v[64];
    float mu = 0.f;
#pragma unroll
    for (int c = 0; c < 64; ++c) { v[c] = ib[(size_t)c * HWP]; mu += v[c]; }
    mu *= (1.f / 64.f);
    float var = 0.f;
#pragma unroll
    for (int c = 0; c < 64; ++c) { float d = v[c] - mu; var += d * d; }
    var *= (1.f / 64.f);
    float r = rsqrtf(var + 1e-6f);
    float* ob = out + (size_t)bb * 64 * HWP + p;
#pragma unroll
    for (int c = 0; c < 64; ++c) ob[(size_t)c * HWP] = (v[c] - mu) * r * w[c] + b[c];
}

// ---------------- 1x1 conv, 8 outputs per thread ----------------
__global__ __launch_bounds__(256) void conv1x1_kernel(
    const float* __restrict__ in, const float* __restrict__ w,
    const float* __restrict__ bias, float* __restrict__ out,
    int Ci, int Co, int do_gelu, int do_add)
{
    int p = blockIdx.x * 256 + threadIdx.x;
    int o0 = blockIdx.y * 8;
    int bb = blockIdx.z;
    if (p >= HWP) return;
    float acc[8];
#pragma unroll
    for (int j = 0; j < 8; ++j) acc[j] = bias[o0 + j];
    const float* ib = in + (size_t)bb * Ci * HWP + p;
    for (int c = 0; c < Ci; ++c) {
        float xv = ib[(size_t)c * HWP];
#pragma unroll
        for (int j = 0; j < 8; ++j) acc[j] += xv * w[(o0 + j) * Ci + c];
    }
    float* ob = out + ((size_t)bb * Co + o0) * HWP + p;
#pragma unroll
    for (int j = 0; j < 8; ++j) {
        float r = do_gelu ? gelu_f(acc[j]) : acc[j];
        if (do_add) ob[(size_t)j * HWP] += r;
        else        ob[(size_t)j * HWP] = r;
    }
}

// ------- fused: gelu(dwconv3x3(in)) + in, then 1x1 proj (Ci -> 64) -------
__global__ __launch_bounds__(256) void dwproj_kernel(
    const float* __restrict__ in,   // (B,Ci,H,W)
    const float* __restrict__ dw,   // (Ci,9)
    const float* __restrict__ db,   // (Ci)
    const float* __restrict__ aw,   // (64,Ci)
    const float* __restrict__ ab,   // (64)
    float* __restrict__ out,        // (B,64,H,W)
    int Ci)
{
    __shared__ __align__(16) float s_aw[128 * 64];  // [c][o], o fastest
    __shared__ float s_dw[128 * 9];
    __shared__ float s_db[128];
    int tid = threadIdx.x;
    for (int i = tid; i < 64 * Ci; i += 256) {
        int o = i / Ci; int c = i - o * Ci;
        s_aw[c * 64 + o] = aw[i];
    }
    for (int i = tid; i < Ci * 9; i += 256) s_dw[i] = dw[i];
    for (int i = tid; i < Ci; i += 256) s_db[i] = db[i];
    __syncthreads();

    int p = blockIdx.x * 256 + tid;
    int bb = blockIdx.y;
    if (p < HWP) {
        int y = p / WW, x = p - y * WW;
        float acc[64];
#pragma unroll
        for (int o = 0; o < 64; ++o) acc[o] = ab[o];
        const float* ib = in + (size_t)bb * Ci * HWP;
        for (int c = 0; c < Ci; ++c) {
            const float* cb = ib + (size_t)c * HWP;
            float center = cb[p];
            float s = s_db[c];
#pragma unroll
            for (int ky = 0; ky < 3; ++ky) {
                int yy = y + ky - 1;
                if ((unsigned)yy >= HH) continue;
#pragma unroll
                for (int kx = 0; kx < 3; ++kx) {
                    int xx = x + kx - 1;
                    if ((unsigned)xx >= WW) continue;
                    s += cb[yy * WW + xx] * s_dw[c * 9 + ky * 3 + kx];
                }
            }
            float v = gelu_f(s) + center;
            const float4* w4 = (const float4*)(s_aw + c * 64);
#pragma unroll
            for (int j = 0; j < 16; ++j) {
                float4 w = w4[j];
                acc[4 * j + 0] += v * w.x;
                acc[4 * j + 1] += v * w.y;
                acc[4 * j + 2] += v * w.z;
                acc[4 * j + 3] += v * w.w;
            }
        }
        float* ob = out + (size_t)bb * 64 * HWP + p;
#pragma unroll
        for (int o = 0; o < 64; ++o) ob[(size_t)o * HWP] = acc[o];
    }
}

// ---------------- fused window attention: one block = (window, head) ----------------
__global__ __launch_bounds__(128) void winattn_kernel(
    const float* __restrict__ xin,  // LN'd x (B,64,H,W)
    const float* __restrict__ qkvw, // (192,64)
    const float* __restrict__ qkvb, // (192)
    const float* __restrict__ rpb,  // (8,361)
    float* __restrict__ out)        // (B,64,H,W)
{
    __shared__ __align__(16) float s_wq[8][64];
    __shared__ __align__(16) float s_wk[8][64];
    __shared__ __align__(16) float s_wv[8][64];
    __shared__ __align__(16) float s_k[100][8];
    __shared__ __align__(16) float s_v[100][8];
    __shared__ float s_b[361];

    int head = blockIdx.y, bb = blockIdx.z;
    int wy = blockIdx.x / 20, wx = blockIdx.x - wy * 20;
    int tid = threadIdx.x;

    for (int i = tid; i < 8 * 64; i += 128) {
        (&s_wq[0][0])[i] = qkvw[(head * 8) * 64 + i];
        (&s_wk[0][0])[i] = qkvw[(64 + head * 8) * 64 + i];
        (&s_wv[0][0])[i] = qkvw[(128 + head * 8) * 64 + i];
    }
    for (int i = tid; i < 361; i += 128) s_b[i] = rpb[head * 361 + i];
    __syncthreads();

    float q[8];
    int ty = tid / 10, tx = tid - ty * 10;
    if (tid < 100) {
        int y = wy * 10 + ty, x = wx * 10 + tx;
        const float* xb = xin + (size_t)bb * 64 * HWP + y * WW + x;
        float xr[64];
#pragma unroll
        for (int c = 0; c < 64; ++c) xr[c] = xb[(size_t)c * HWP];
#pragma unroll
        for (int cc = 0; cc < 8; ++cc) {
            float aq = qkvb[head * 8 + cc];
            float ak = qkvb[64 + head * 8 + cc];
            float av = qkvb[128 + head * 8 + cc];
#pragma unroll
            for (int c = 0; c < 64; ++c) {
                float xv = xr[c];
                aq += xv * s_wq[cc][c];
                ak += xv * s_wk[cc][c];
                av += xv * s_wv[cc][c];
            }
            q[cc] = aq;
            s_k[tid][cc] = ak;
            s_v[tid][cc] = av;
        }
    }
    __syncthreads();

    if (tid < 100) {
        const float scale = 0.3535533905932738f; // 1/sqrt(8)
        const float4* k4 = (const float4*)s_k;
        const float4* v4 = (const float4*)s_v;
        // pass 1: max
        float m = -1e30f;
        {
            int ky = 0, kx = 0;
            for (int kk = 0; kk < 100; ++kk) {
                float4 ka = k4[kk * 2], kb = k4[kk * 2 + 1];
                float s = q[0] * ka.x + q[1] * ka.y + q[2] * ka.z + q[3] * ka.w
                        + q[4] * kb.x + q[5] * kb.y + q[6] * kb.z + q[7] * kb.w;
                s = s * scale + s_b[(ky - ty + 9) * 19 + (kx - tx + 9)];
                m = fmaxf(m, s);
                if (++kx == 10) { kx = 0; ++ky; }
            }
        }
        // pass 2: sum + PV
        float l = 0.f;
        float o[8];
#pragma unroll
        for (int cc = 0; cc < 8; ++cc) o[cc] = 0.f;
        {
            int ky = 0, kx = 0;
            for (int kk = 0; kk < 100; ++kk) {
                float4 ka = k4[kk * 2], kb = k4[kk * 2 + 1];
                float s = q[0] * ka.x + q[1] * ka.y + q[2] * ka.z + q[3] * ka.w
                        + q[4] * kb.x + q[5] * kb.y + q[6] * kb.z + q[7] * kb.w;
                s = s * scale + s_b[(ky - ty + 9) * 19 + (kx - tx + 9)];
                float e = expf(s - m);
                l += e;
                float4 va = v4[kk * 2], vb = v4[kk * 2 + 1];
                o[0] += e * va.x; o[1] += e * va.y; o[2] += e * va.z; o[3] += e * va.w;
                o[4] += e * vb.x; o[5] += e * vb.y; o[6] += e * vb.z; o[7] += e * vb.w;
                if (++kx == 10) { kx = 0; ++ky; }
            }
        }
        float rl = 1.f / l;
        int y = wy * 10 + ty, x = wx * 10 + tx;
        float* ob = out + ((size_t)bb * 64 + head * 8) * HWP + y * WW + x;
#pragma unroll
        for (int cc = 0; cc < 8; ++cc) ob[(size_t)cc * HWP] = o[cc] * rl;
    }
}

// ---------------- geometric ensemble of 13x13 filter ----------------
__global__ __launch_bounds__(256) void geo_kernel(
    const float* __restrict__ k, float* __restrict__ out)
{
    int i = blockIdx.x * 256 + threadIdx.x;
    if (i >= 16 * 16 * 169) return;
    int oc = i / 169;
    int t = i - oc * 169;
    int y = t / 13, x = t - y * 13;
    const float* kb = k + oc * 169;
    float s = kb[y * 13 + x] + kb[y * 13 + (12 - x)] + kb[(12 - y) * 13 + x] + kb[(12 - y) * 13 + (12 - x)]
            + kb[(12 - x) * 13 + y] + kb[x * 13 + y] + kb[(12 - x) * 13 + (12 - y)] + kb[x * 13 + (12 - y)];
    out[i] = s * 0.125f;
}

// ---------------- global mean over H,W of first-16 channels ----------------
__global__ __launch_bounds__(256) void gmean_kernel(
    const float* __restrict__ in, float* __restrict__ g)
{
    int bc = blockIdx.x;            // b*16 + c
    int bb = bc >> 4, c = bc & 15;
    const float* p = in + ((size_t)bb * 64 + c) * HWP;
    float s = 0.f;
    for (int i = threadIdx.x; i < HWP; i += 256) s += p[i];
#pragma unroll
    for (int off = 32; off > 0; off >>= 1) s += __shfl_down(s, off);
    __shared__ float red[4];
    int wave = threadIdx.x >> 6;
    if ((threadIdx.x & 63) == 0) red[wave] = s;
    __syncthreads();
    if (threadIdx.x == 0)
        g[bc] = (red[0] + red[1] + red[2] + red[3]) * (1.f / 40000.f);
}

// ---------------- tiny MLP: g -> gelu(W1 g) -> W2 -> dynamic 3x3 kernels ----------------
__global__ __launch_bounds__(192) void dynk_kernel(
    const float* __restrict__ g, const float* __restrict__ w1, const float* __restrict__ b1,
    const float* __restrict__ w2, const float* __restrict__ b2, float* __restrict__ dk)
{
    int bb = blockIdx.x;
    __shared__ float s_g2[8];
    int tid = threadIdx.x;
    if (tid < 8) {
        float a = b1[tid];
        for (int c = 0; c < 16; ++c) a += w1[tid * 16 + c] * g[bb * 16 + c];
        s_g2[tid] = gelu_f(a);
    }
    __syncthreads();
    if (tid < 144) {
        float a = b2[tid];
#pragma unroll
        for (int i = 0; i < 8; ++i) a += w2[tid * 8 + i] * s_g2[i];
        dk[bb * 144 + tid] = a;
    }
}

// ------- 13x13 conv (16->16, pad 6) + dynamic depthwise 3x3 (pad 1), no bias -------
__global__ __launch_bounds__(256) void lkconv_kernel(
    const float* __restrict__ in,   // (B,64,H,W) — channels 0..15 used
    const float* __restrict__ lk,   // (16,16,13,13)
    const float* __restrict__ dk,   // (B,144)
    float* __restrict__ out)        // (B,16,H,W)
{
    __shared__ __align__(16) float s_p[28 * 28];
    __shared__ __align__(16) float s_w[169 * 16];   // [tap][co]
    int bb = blockIdx.z;
    int tx = threadIdx.x, ty = threadIdx.y;
    int tid = ty * 16 + tx;
    int x0 = blockIdx.x * 16, y0 = blockIdx.y * 16;
    int x = x0 + tx, y = y0 + ty;
    float acc[16];
#pragma unroll
    for (int co = 0; co < 16; ++co) acc[co] = 0.f;

    for (int ci = 0; ci < 16; ++ci) {
        __syncthreads();
        const float* cb = in + ((size_t)bb * 64 + ci) * HWP;
        for (int i = tid; i < 28 * 28; i += 256) {
            int py = i / 28, px = i - py * 28;
            int yy = y0 + py - 6, xx = x0 + px - 6;
            float v = 0.f;
            if ((unsigned)yy < HH && (unsigned)xx < WW) v = cb[yy * WW + xx];
            s_p[i] = v;
        }
        for (int i = tid; i < 169 * 16; i += 256) {
            int tap = i >> 4, co = i & 15;
            s_w[i] = lk[((co * 16 + ci) * 169) + tap];
        }
        __syncthreads();

        for (int ky = 0; ky < 13; ++ky) {
#pragma unroll
            for (int kx = 0; kx < 13; ++kx) {
                float xv = s_p[(ty + ky) * 28 + tx + kx];
                const float4* w4 = (const float4*)(s_w + (ky * 13 + kx) * 16);
#pragma unroll
                for (int j = 0; j < 4; ++j) {
                    float4 w = w4[j];
                    acc[4 * j + 0] += xv * w.x;
                    acc[4 * j + 1] += xv * w.y;
                    acc[4 * j + 2] += xv * w.z;
                    acc[4 * j + 3] += xv * w.w;
                }
            }
        }
        // dynamic depthwise 3x3 contributes to output channel == ci
        float d = 0.f;
#pragma unroll
        for (int dy = 0; dy < 3; ++dy)
#pragma unroll
            for (int dx = 0; dx < 3; ++dx)
                d += s_p[(ty + 5 + dy) * 28 + tx + 5 + dx] * dk[bb * 144 + ci * 9 + dy * 3 + dx];
#pragma unroll
        for (int co = 0; co < 16; ++co) acc[co] += (co == ci) ? d : 0.f;
    }

    if (x < WW && y < HH) {
        int p = y * WW + x;
        float* ob = out + (size_t)bb * 16 * HWP + p;
#pragma unroll
        for (int co = 0; co < 16; ++co) ob[(size_t)co * HWP] = acc[co];
    }
}

// ------- 1x1 conv over concat(x1[0..15], y[16..63]) and add into xout -------
__global__ __launch_bounds__(256) void pconv_add_kernel(
    const float* __restrict__ x1,   // (B,16,H,W)
    const float* __restrict__ yy,   // (B,64,H,W), channels 16..63 used
    const float* __restrict__ w,    // (64,64)
    const float* __restrict__ bias, // (64)
    float* __restrict__ xout)       // (B,64,H,W), +=
{
    int p = blockIdx.x * 256 + threadIdx.x;
    int o0 = blockIdx.y * 8;
    int bb = blockIdx.z;
    if (p >= HWP) return;
    float acc[8];
#pragma unroll
    for (int j = 0; j < 8; ++j) acc[j] = bias[o0 + j];
    const float* xb = x1 + (size_t)bb * 16 * HWP + p;
    for (int c = 0; c < 16; ++c) {
        float xv = xb[(size_t)c * HWP];
#pragma unroll
        for (int j = 0; j < 8; ++j) acc[j] += xv * w[(o0 + j) * 64 + c];
    }
    const float* yb = yy + ((size_t)bb * 64 + 16) * HWP + p;
    for (int c = 0; c < 48; ++c) {
        float xv = yb[(size_t)c * HWP];
#pragma unroll
        for (int j = 0; j < 8; ++j) acc[j] += xv * w[(o0 + j) * 64 + 16 + c];
    }
    float* ob = xout + ((size_t)bb * 64 + o0) * HWP + p;
#pragma unroll
    for (int j = 0; j < 8; ++j) ob[(size_t)j * HWP] += acc[j];
}

// ---------------- final 3x3 conv (64->64, pad 1) + bias + skip ----------------
__global__ __launch_bounds__(256) void conv3_skip_kernel(
    const float* __restrict__ in, const float* __restrict__ w,
    const float* __restrict__ bias, const float* __restrict__ skip,
    float* __restrict__ out)
{
    int p = blockIdx.x * 256 + threadIdx.x;
    int o0 = blockIdx.y * 8;
    int bb = blockIdx.z;
    if (p >= HWP) return;
    int y = p / WW, x = p - y * WW;
    float acc[8];
#pragma unroll
    for (int j = 0; j < 8; ++j) acc[j] = bias[o0 + j];
    const float* ib = in + (size_t)bb * 64 * HWP;
    for (int c = 0; c < 64; ++c) {
        const float* cb = ib + (size_t)c * HWP;
#pragma unroll
        for (int ky = 0; ky < 3; ++ky) {
            int yy = y + ky - 1;
            if ((unsigned)yy >= HH) continue;
#pragma unroll
            for (int kx = 0; kx < 3; ++kx) {
                int xx = x + kx - 1;
                if ((unsigned)xx >= WW) continue;
                float xv = cb[yy * WW + xx];
#pragma unroll
                for (int j = 0; j < 8; ++j)
                    acc[j] += xv * w[((o0 + j) * 64 + c) * 9 + ky * 3 + kx];
            }
        }
    }
    const float* sb = skip + ((size_t)bb * 64 + o0) * HWP + p;
    float* ob = out + ((size_t)bb * 64 + o0) * HWP + p;
#pragma unroll
    for (int j = 0; j < 8; ++j) ob[(size_t)j * HWP] = acc[j] + sb[(size_t)j * HWP];
}

extern "C" void kernel_launch(void* const* d_in, const int* in_sizes, int n_in,
                              void* d_out, int out_size, void* d_ws, size_t ws_size,
                              hipStream_t stream)
{
    const float* x_in      = (const float*)d_in[0];
    const float* ln_proj_w = (const float*)d_in[1];
    const float* ln_proj_b = (const float*)d_in[2];
    const float* proj_p_w  = (const float*)d_in[3];
    const float* proj_p_b  = (const float*)d_in[4];
    const float* proj_d_w  = (const float*)d_in[5];
    const float* proj_d_b  = (const float*)d_in[6];
    const float* proj_a_w  = (const float*)d_in[7];
    const float* proj_a_b  = (const float*)d_in[8];
    const float* ln_attn_w = (const float*)d_in[9];
    const float* ln_attn_b = (const float*)d_in[10];
    const float* qkv_w     = (const float*)d_in[11];
    const float* qkv_b     = (const float*)d_in[12];
    const float* attn_o_w  = (const float*)d_in[13];
    const float* attn_o_b  = (const float*)d_in[14];
    const float* rpb       = (const float*)d_in[15];
    const float* dwcp1_w   = (const float*)d_in[16];
    const float* dwcp1_b   = (const float*)d_in[17];
    const float* dwcp2_w   = (const float*)d_in[18];
    const float* dwcp2_b   = (const float*)d_in[19];
    const float* pconv_w   = (const float*)d_in[20];
    const float* pconv_b   = (const float*)d_in[21];
    const float* ffn_p_w   = (const float*)d_in[22];
    const float* ffn_p_b   = (const float*)d_in[23];
    const float* ffn_d_w   = (const float*)d_in[24];
    const float* ffn_d_b   = (const float*)d_in[25];
    const float* ffn_a_w   = (const float*)d_in[26];
    const float* ffn_a_b   = (const float*)d_in[27];
    const float* ln_out_w  = (const float*)d_in[28];
    const float* ln_out_b  = (const float*)d_in[29];
    const float* conv_o_w  = (const float*)d_in[30];
    const float* conv_o_b  = (const float*)d_in[31];
    const float* plk       = (const float*)d_in[32];

    float* X  = (float*)d_out;                 // running x, 4*64*40000
    float* ws = (float*)d_ws;
    float* A  = ws;                            // 10.24M floats
    float* R1 = ws + 10240000;                 // 20.48M floats (up to 128ch)
    float* R2 = ws + 30720000;                 // 2.56M floats (16ch)
    float* LK = ws + 33280000;                 // 43264
    float* GM = LK + 43264;                    // 64
    float* DK = GM + 64;                       // 576

    dim3 b256(256);
    dim3 gP(157, 4);

    // x = LN(x); x = conv_ffn(x) [proj]
    ln_kernel<<<gP, b256, 0, stream>>>(x_in, ln_proj_w, ln_proj_b, A);
    conv1x1_kernel<<<dim3(157, 16, 4), b256, 0, stream>>>(A, proj_p_w, proj_p_b, R1, 64, 128, 1, 0);
    dwproj_kernel<<<gP, b256, 0, stream>>>(R1, proj_d_w, proj_d_b, proj_a_w, proj_a_b, X, 128);

    // x = x + window_attention(LN(x))
    ln_kernel<<<gP, b256, 0, stream>>>(X, ln_attn_w, ln_attn_b, A);
    winattn_kernel<<<dim3(400, 8, 4), dim3(128), 0, stream>>>(A, qkv_w, qkv_b, rpb, R1);
    conv1x1_kernel<<<dim3(157, 8, 4), b256, 0, stream>>>(R1, attn_o_w, attn_o_b, X, 64, 64, 0, 1);

    // lk = geo_ensemble(plk)
    geo_kernel<<<dim3(169), b256, 0, stream>>>(plk, LK);

    for (int i = 0; i < 2; ++i) {
        // y = conv_ffn(x)
        conv1x1_kernel<<<dim3(157, 10, 4), b256, 0, stream>>>(X, ffn_p_w + i * 80 * 64, ffn_p_b + i * 80, R1, 64, 80, 1, 0);
        dwproj_kernel<<<gP, b256, 0, stream>>>(R1, ffn_d_w + i * 80 * 9, ffn_d_b + i * 80,
                                               ffn_a_w + i * 64 * 80, ffn_a_b + i * 64, A, 80);
        // y = conv_attention(y, lk)
        gmean_kernel<<<dim3(64), b256, 0, stream>>>(A, GM);
        dynk_kernel<<<dim3(4), dim3(192), 0, stream>>>(GM, dwcp1_w + i * 128, dwcp1_b + i * 8,
                                                       dwcp2_w + i * 1152, dwcp2_b + i * 144, DK);
        lkconv_kernel<<<dim3(13, 13, 4), dim3(16, 16), 0, stream>>>(A, LK, DK, R2);
        // y = pconv_aggr(concat(x1, x2)); x += y
        pconv_add_kernel<<<dim3(157, 8, 4), b256, 0, stream>>>(R2, A, pconv_w + i * 4096, pconv_b + i * 64, X);
    }

    // x = conv3x3(LN(x)) + skip
    ln_kernel<<<gP, b256, 0, stream>>>(X, ln_out_w, ln_out_b, A);
    conv3_skip_kernel<<<dim3(157, 8, 4), b256, 0, stream>>>(A, conv_o_w, conv_o_b, x_in, X);
}

// Round 2
// 1949.245 us; speedup vs baseline: 1.8685x; 1.8685x over previous
//
#include <hip/hip_runtime.h>
#include <math.h>

#define HH 200
#define WW 200
#define HWP 40000
#define NP4 10000
#define BB 4

__device__ __forceinline__ float gelu_f(float x) {
    return 0.5f * x * (1.0f + erff(x * 0.7071067811865475f));
}

// ---------------- weight prep: transposes so conv kernels use scalar (SGPR) weight loads ----
// wt layout offsets (floats):
//  0      wtP   (64,128)   proj_p
//  8192   wtAO  (64,64)    attn_out
//  12288  wtFP0 (64,80)    ffn_p[0]
//  17408  wtFP1 (64,80)    ffn_p[1]
//  22528  wtPA  (128,64)   proj_a
//  30720  wtFA0 (80,64)    ffn_a[0]
//  35840  wtFA1 (80,64)    ffn_a[1]
//  40960  wtPC0 (64,64)    pconv[0]
//  45056  wtPC1 (64,64)    pconv[1]
//  49152  wt3   (64,9,64)  conv_out  [ci][tap][co]
__device__ __forceinline__ void tr_w(const float* __restrict__ w, float* __restrict__ wt,
                                     int Co, int Ci, int idx) {
    int o = idx / Ci, c = idx - o * Ci;
    wt[c * Co + o] = w[idx];
}

__global__ __launch_bounds__(256) void prep_kernel(
    const float* __restrict__ pp, const float* __restrict__ ao,
    const float* __restrict__ fp, const float* __restrict__ pa,
    const float* __restrict__ fa, const float* __restrict__ pc,
    const float* __restrict__ co3, float* __restrict__ wt)
{
    int i = blockIdx.x * 256 + threadIdx.x;
    if (i < 8192) { tr_w(pp, wt + 0, 128, 64, i); return; } i -= 8192;
    if (i < 4096) { tr_w(ao, wt + 8192, 64, 64, i); return; } i -= 4096;
    if (i < 5120) { tr_w(fp, wt + 12288, 80, 64, i); return; } i -= 5120;
    if (i < 5120) { tr_w(fp + 5120, wt + 17408, 80, 64, i); return; } i -= 5120;
    if (i < 8192) { tr_w(pa, wt + 22528, 64, 128, i); return; } i -= 8192;
    if (i < 5120) { tr_w(fa, wt + 30720, 64, 80, i); return; } i -= 5120;
    if (i < 5120) { tr_w(fa + 5120, wt + 35840, 64, 80, i); return; } i -= 5120;
    if (i < 4096) { tr_w(pc, wt + 40960, 64, 64, i); return; } i -= 4096;
    if (i < 4096) { tr_w(pc + 4096, wt + 45056, 64, 64, i); return; } i -= 4096;
    if (i < 36864) {
        int o = i / 576; int r = i - o * 576; int c = r / 9; int t = r - c * 9;
        wt[49152 + (c * 9 + t) * 64 + o] = co3[i];
    }
}

// ---------------- LayerNorm over 64 channels ----------------
__global__ __launch_bounds__(256) void ln_kernel(
    const float* __restrict__ in, const float* __restrict__ w,
    const float* __restrict__ b, float* __restrict__ out)
{
    int p = blockIdx.x * 256 + threadIdx.x;
    int bb = blockIdx.y;
    if (p >= HWP) return;
    const float* ib = in + (size_t)bb * 64 * HWP + p;
    float v[64];
    float mu = 0.f;
#pragma unroll
    for (int c = 0; c < 64; ++c) { v[c] = ib[(size_t)c * HWP]; mu += v[c]; }
    mu *= (1.f / 64.f);
    float var = 0.f;
#pragma unroll
    for (int c = 0; c < 64; ++c) { float d = v[c] - mu; var += d * d; }
    var *= (1.f / 64.f);
    float r = rsqrtf(var + 1e-6f);
    float* ob = out + (size_t)bb * 64 * HWP + p;
#pragma unroll
    for (int c = 0; c < 64; ++c) ob[(size_t)c * HWP] = (v[c] - mu) * r * w[c] + b[c];
}

// ---------------- 1x1 conv: float4 pixels, 16 outputs/thread, scalar weights ----------------
__global__ __launch_bounds__(256) void conv1x1_kernel(
    const float* __restrict__ in, const float* __restrict__ wt,  // (Ci,Co)
    const float* __restrict__ bias, float* __restrict__ out,
    int Ci, int Co, int do_gelu, int do_add)
{
    int p4 = blockIdx.x * 256 + threadIdx.x;
    int o0 = blockIdx.y * 16;
    int bb = blockIdx.z;
    if (p4 >= NP4) return;
    float4 acc[16];
#pragma unroll
    for (int j = 0; j < 16; ++j) {
        float bv = bias[o0 + j];
        acc[j] = make_float4(bv, bv, bv, bv);
    }
    const float4* ib = (const float4*)(in + (size_t)bb * Ci * HWP) + p4;
    for (int c = 0; c < Ci; ++c) {
        float4 xv = ib[(size_t)c * NP4];
        const float* wr = wt + c * Co + o0;
#pragma unroll
        for (int j = 0; j < 16; ++j) {
            float w = wr[j];
            acc[j].x += xv.x * w; acc[j].y += xv.y * w;
            acc[j].z += xv.z * w; acc[j].w += xv.w * w;
        }
    }
    float4* ob = (float4*)(out + ((size_t)bb * Co + o0) * HWP) + p4;
#pragma unroll
    for (int j = 0; j < 16; ++j) {
        float4 r = acc[j];
        if (do_gelu) {
            r.x = gelu_f(r.x); r.y = gelu_f(r.y); r.z = gelu_f(r.z); r.w = gelu_f(r.w);
        }
        if (do_add) {
            float4 old = ob[(size_t)j * NP4];
            r.x += old.x; r.y += old.y; r.z += old.z; r.w += old.w;
        }
        ob[(size_t)j * NP4] = r;
    }
}

// ------- fused: gelu(dwconv3x3(in)) + in, then 1x1 proj (Ci -> 64), LDS-tiled -------
__global__ __launch_bounds__(256) void dwproj_kernel(
    const float* __restrict__ in,   // (B,Ci,H,W)
    const float* __restrict__ dw,   // (Ci,9)
    const float* __restrict__ db,   // (Ci)
    const float* __restrict__ awt,  // (Ci,64) transposed
    const float* __restrict__ ab,   // (64)
    float* __restrict__ out,        // (B,64,H,W)
    int Ci)
{
    __shared__ float s_p[18 * 18];
    int tid = threadIdx.x;
    int tx = tid & 15, ty = tid >> 4;
    int x0 = blockIdx.x * 16, y0 = blockIdx.y * 16;
    int bb = blockIdx.z;
    int x = x0 + tx, y = y0 + ty;

    float acc[64];
#pragma unroll
    for (int o = 0; o < 64; ++o) acc[o] = ab[o];

    const float* ibase = in + (size_t)bb * Ci * HWP;
    for (int ci = 0; ci < Ci; ++ci) {
        __syncthreads();
        const float* cb = ibase + (size_t)ci * HWP;
        for (int i = tid; i < 18 * 18; i += 256) {
            int py = i / 18, px = i - py * 18;
            int yy = y0 + py - 1, xx = x0 + px - 1;
            float v = 0.f;
            if ((unsigned)yy < HH && (unsigned)xx < WW) v = cb[yy * WW + xx];
            s_p[i] = v;
        }
        __syncthreads();
        float s = db[ci];
#pragma unroll
        for (int ky = 0; ky < 3; ++ky)
#pragma unroll
            for (int kx = 0; kx < 3; ++kx)
                s += s_p[(ty + ky) * 18 + tx + kx] * dw[ci * 9 + ky * 3 + kx];
        float v = gelu_f(s) + s_p[(ty + 1) * 18 + tx + 1];
        const float* wr = awt + ci * 64;
#pragma unroll
        for (int o = 0; o < 64; ++o) acc[o] += v * wr[o];
    }

    if (x < WW && y < HH) {
        int p = y * WW + x;
        float* ob = out + (size_t)bb * 64 * HWP + p;
#pragma unroll
        for (int o = 0; o < 64; ++o) ob[(size_t)o * HWP] = acc[o];
    }
}

// ---------------- fused window attention: one block = (window, head) ----------------
__global__ __launch_bounds__(128) void winattn_kernel(
    const float* __restrict__ xin,  // LN'd x (B,64,H,W)
    const float* __restrict__ qkvw, // (192,64)
    const float* __restrict__ qkvb, // (192)
    const float* __restrict__ rpb,  // (8,361)
    float* __restrict__ out)        // (B,64,H,W)
{
    __shared__ __align__(16) float s_wq[8][64];
    __shared__ __align__(16) float s_wk[8][64];
    __shared__ __align__(16) float s_wv[8][64];
    __shared__ __align__(16) float s_k[100][8];
    __shared__ __align__(16) float s_v[100][8];
    __shared__ float s_b[361];

    int head = blockIdx.y, bb = blockIdx.z;
    int wy = blockIdx.x / 20, wx = blockIdx.x - wy * 20;
    int tid = threadIdx.x;

    for (int i = tid; i < 8 * 64; i += 128) {
        (&s_wq[0][0])[i] = qkvw[(head * 8) * 64 + i];
        (&s_wk[0][0])[i] = qkvw[(64 + head * 8) * 64 + i];
        (&s_wv[0][0])[i] = qkvw[(128 + head * 8) * 64 + i];
    }
    for (int i = tid; i < 361; i += 128) s_b[i] = rpb[head * 361 + i];
    __syncthreads();

    float q[8];
    int ty = tid / 10, tx = tid - ty * 10;
    if (tid < 100) {
        int y = wy * 10 + ty, x = wx * 10 + tx;
        const float* xb = xin + (size_t)bb * 64 * HWP + y * WW + x;
        float xr[64];
#pragma unroll
        for (int c = 0; c < 64; ++c) xr[c] = xb[(size_t)c * HWP];
#pragma unroll
        for (int cc = 0; cc < 8; ++cc) {
            float aq = qkvb[head * 8 + cc];
            float ak = qkvb[64 + head * 8 + cc];
            float av = qkvb[128 + head * 8 + cc];
#pragma unroll
            for (int c = 0; c < 64; ++c) {
                float xv = xr[c];
                aq += xv * s_wq[cc][c];
                ak += xv * s_wk[cc][c];
                av += xv * s_wv[cc][c];
            }
            q[cc] = aq;
            s_k[tid][cc] = ak;
            s_v[tid][cc] = av;
        }
    }
    __syncthreads();

    if (tid < 100) {
        const float scale = 0.3535533905932738f; // 1/sqrt(8)
        const float4* k4 = (const float4*)s_k;
        const float4* v4 = (const float4*)s_v;
        float m = -1e30f;
        {
            int ky = 0, kx = 0;
            for (int kk = 0; kk < 100; ++kk) {
                float4 ka = k4[kk * 2], kb = k4[kk * 2 + 1];
                float s = q[0] * ka.x + q[1] * ka.y + q[2] * ka.z + q[3] * ka.w
                        + q[4] * kb.x + q[5] * kb.y + q[6] * kb.z + q[7] * kb.w;
                s = s * scale + s_b[(ky - ty + 9) * 19 + (kx - tx + 9)];
                m = fmaxf(m, s);
                if (++kx == 10) { kx = 0; ++ky; }
            }
        }
        float l = 0.f;
        float o[8];
#pragma unroll
        for (int cc = 0; cc < 8; ++cc) o[cc] = 0.f;
        {
            int ky = 0, kx = 0;
            for (int kk = 0; kk < 100; ++kk) {
                float4 ka = k4[kk * 2], kb = k4[kk * 2 + 1];
                float s = q[0] * ka.x + q[1] * ka.y + q[2] * ka.z + q[3] * ka.w
                        + q[4] * kb.x + q[5] * kb.y + q[6] * kb.z + q[7] * kb.w;
                s = s * scale + s_b[(ky - ty + 9) * 19 + (kx - tx + 9)];
                float e = expf(s - m);
                l += e;
                float4 va = v4[kk * 2], vb = v4[kk * 2 + 1];
                o[0] += e * va.x; o[1] += e * va.y; o[2] += e * va.z; o[3] += e * va.w;
                o[4] += e * vb.x; o[5] += e * vb.y; o[6] += e * vb.z; o[7] += e * vb.w;
                if (++kx == 10) { kx = 0; ++ky; }
            }
        }
        float rl = 1.f / l;
        int y = wy * 10 + ty, x = wx * 10 + tx;
        float* ob = out + ((size_t)bb * 64 + head * 8) * HWP + y * WW + x;
#pragma unroll
        for (int cc = 0; cc < 8; ++cc) ob[(size_t)cc * HWP] = o[cc] * rl;
    }
}

// ------- geometric ensemble of 13x13 filter -> transposed (ci,tap,co) layout -------
__global__ __launch_bounds__(256) void geo_kernel(
    const float* __restrict__ k, float* __restrict__ out)
{
    int i = blockIdx.x * 256 + threadIdx.x;
    if (i >= 16 * 16 * 169) return;
    int oc = i / 169;                 // co*16 + ci
    int co = oc >> 4, ci = oc & 15;
    int t = i - oc * 169;
    int y = t / 13, x = t - y * 13;
    const float* kb = k + oc * 169;
    float s = kb[y * 13 + x] + kb[y * 13 + (12 - x)] + kb[(12 - y) * 13 + x] + kb[(12 - y) * 13 + (12 - x)]
            + kb[(12 - x) * 13 + y] + kb[x * 13 + y] + kb[(12 - x) * 13 + (12 - y)] + kb[x * 13 + (12 - y)];
    out[(ci * 169 + t) * 16 + co] = s * 0.125f;
}

// ---------------- global mean over H,W of first-16 channels ----------------
__global__ __launch_bounds__(256) void gmean_kernel(
    const float* __restrict__ in, float* __restrict__ g)
{
    int bc = blockIdx.x;            // b*16 + c
    int bb = bc >> 4, c = bc & 15;
    const float* p = in + ((size_t)bb * 64 + c) * HWP;
    float s = 0.f;
    for (int i = threadIdx.x; i < HWP; i += 256) s += p[i];
#pragma unroll
    for (int off = 32; off > 0; off >>= 1) s += __shfl_down(s, off);
    __shared__ float red[4];
    int wave = threadIdx.x >> 6;
    if ((threadIdx.x & 63) == 0) red[wave] = s;
    __syncthreads();
    if (threadIdx.x == 0)
        g[bc] = (red[0] + red[1] + red[2] + red[3]) * (1.f / 40000.f);
}

// ---------------- tiny MLP: g -> gelu(W1 g) -> W2 -> dynamic 3x3 kernels ----------------
__global__ __launch_bounds__(192) void dynk_kernel(
    const float* __restrict__ g, const float* __restrict__ w1, const float* __restrict__ b1,
    const float* __restrict__ w2, const float* __restrict__ b2, float* __restrict__ dk)
{
    int bb = blockIdx.x;
    __shared__ float s_g2[8];
    int tid = threadIdx.x;
    if (tid < 8) {
        float a = b1[tid];
        for (int c = 0; c < 16; ++c) a += w1[tid * 16 + c] * g[bb * 16 + c];
        s_g2[tid] = gelu_f(a);
    }
    __syncthreads();
    if (tid < 144) {
        float a = b2[tid];
#pragma unroll
        for (int i = 0; i < 8; ++i) a += w2[tid * 8 + i] * s_g2[i];
        dk[bb * 144 + tid] = a;
    }
}

// ------- 13x13 conv (16->16, pad 6) + dynamic depthwise 3x3 (pad 1), no bias -------
// weights pre-transposed (ci,tap,co) -> scalar loads
__global__ __launch_bounds__(256) void lkconv_kernel(
    const float* __restrict__ in,   // (B,64,H,W) — channels 0..15 used
    const float* __restrict__ lkT,  // (16,169,16)
    const float* __restrict__ dk,   // (B,144)
    float* __restrict__ out)        // (B,16,H,W)
{
    __shared__ float s_p[28 * 28];
    int bb = blockIdx.z;
    int tid = threadIdx.x;
    int tx = tid & 15, ty = tid >> 4;
    int x0 = blockIdx.x * 16, y0 = blockIdx.y * 16;
    int x = x0 + tx, y = y0 + ty;
    float acc[16];
#pragma unroll
    for (int co = 0; co < 16; ++co) acc[co] = 0.f;

    for (int ci = 0; ci < 16; ++ci) {
        __syncthreads();
        const float* cb = in + ((size_t)bb * 64 + ci) * HWP;
        for (int i = tid; i < 28 * 28; i += 256) {
            int py = i / 28, px = i - py * 28;
            int yy = y0 + py - 6, xx = x0 + px - 6;
            float v = 0.f;
            if ((unsigned)yy < HH && (unsigned)xx < WW) v = cb[yy * WW + xx];
            s_p[i] = v;
        }
        __syncthreads();

        const float* wci = lkT + ci * 169 * 16;
        for (int ky = 0; ky < 13; ++ky) {
#pragma unroll
            for (int kx = 0; kx < 13; ++kx) {
                float xv = s_p[(ty + ky) * 28 + tx + kx];
                const float* wr = wci + (ky * 13 + kx) * 16;
#pragma unroll
                for (int co = 0; co < 16; ++co) acc[co] += xv * wr[co];
            }
        }
        // dynamic depthwise 3x3 contributes to output channel == ci
        float d = 0.f;
#pragma unroll
        for (int dy = 0; dy < 3; ++dy)
#pragma unroll
            for (int dx = 0; dx < 3; ++dx)
                d += s_p[(ty + 5 + dy) * 28 + tx + 5 + dx] * dk[bb * 144 + ci * 9 + dy * 3 + dx];
#pragma unroll
        for (int co = 0; co < 16; ++co) acc[co] += (co == ci) ? d : 0.f;
    }

    if (x < WW && y < HH) {
        int p = y * WW + x;
        float* ob = out + (size_t)bb * 16 * HWP + p;
#pragma unroll
        for (int co = 0; co < 16; ++co) ob[(size_t)co * HWP] = acc[co];
    }
}

// ------- 1x1 conv over concat(x1[0..15], y[16..63]) and add into xout -------
__global__ __launch_bounds__(256) void pconv_add_kernel(
    const float* __restrict__ x1,   // (B,16,H,W)
    const float* __restrict__ yy,   // (B,64,H,W), channels 16..63 used
    const float* __restrict__ wt,   // (64,64) transposed (ci,co)
    const float* __restrict__ bias, // (64)
    float* __restrict__ xout)       // (B,64,H,W), +=
{
    int p4 = blockIdx.x * 256 + threadIdx.x;
    int o0 = blockIdx.y * 16;
    int bb = blockIdx.z;
    if (p4 >= NP4) return;
    float4 acc[16];
#pragma unroll
    for (int j = 0; j < 16; ++j) {
        float bv = bias[o0 + j];
        acc[j] = make_float4(bv, bv, bv, bv);
    }
    const float4* xb = (const float4*)(x1 + (size_t)bb * 16 * HWP) + p4;
    for (int c = 0; c < 16; ++c) {
        float4 xv = xb[(size_t)c * NP4];
        const float* wr = wt + c * 64 + o0;
#pragma unroll
        for (int j = 0; j < 16; ++j) {
            float w = wr[j];
            acc[j].x += xv.x * w; acc[j].y += xv.y * w;
            acc[j].z += xv.z * w; acc[j].w += xv.w * w;
        }
    }
    const float4* yb = (const float4*)(yy + ((size_t)bb * 64 + 16) * HWP) + p4;
    for (int c = 0; c < 48; ++c) {
        float4 xv = yb[(size_t)c * NP4];
        const float* wr = wt + (16 + c) * 64 + o0;
#pragma unroll
        for (int j = 0; j < 16; ++j) {
            float w = wr[j];
            acc[j].x += xv.x * w; acc[j].y += xv.y * w;
            acc[j].z += xv.z * w; acc[j].w += xv.w * w;
        }
    }
    float4* ob = (float4*)(xout + ((size_t)bb * 64 + o0) * HWP) + p4;
#pragma unroll
    for (int j = 0; j < 16; ++j) {
        float4 old = ob[(size_t)j * NP4];
        old.x += acc[j].x; old.y += acc[j].y; old.z += acc[j].z; old.w += acc[j].w;
        ob[(size_t)j * NP4] = old;
    }
}

// ---------------- final 3x3 conv (64->64, pad 1) + bias + skip, LDS-tiled ----------------
__global__ __launch_bounds__(256) void conv3_skip_kernel(
    const float* __restrict__ in, const float* __restrict__ wt3,  // (ci,tap,co)
    const float* __restrict__ bias, const float* __restrict__ skip,
    float* __restrict__ out)
{
    __shared__ float s_p[18 * 18];
    int tid = threadIdx.x;
    int tx = tid & 15, ty = tid >> 4;
    int x0 = blockIdx.x * 16, y0 = blockIdx.y * 16;
    int bb = blockIdx.z;
    int x = x0 + tx, y = y0 + ty;

    float acc[64];
#pragma unroll
    for (int o = 0; o < 64; ++o) acc[o] = bias[o];

    const float* ibase = in + (size_t)bb * 64 * HWP;
    for (int ci = 0; ci < 64; ++ci) {
        __syncthreads();
        const float* cb = ibase + (size_t)ci * HWP;
        for (int i = tid; i < 18 * 18; i += 256) {
            int py = i / 18, px = i - py * 18;
            int yy = y0 + py - 1, xx = x0 + px - 1;
            float v = 0.f;
            if ((unsigned)yy < HH && (unsigned)xx < WW) v = cb[yy * WW + xx];
            s_p[i] = v;
        }
        __syncthreads();
#pragma unroll
        for (int ky = 0; ky < 3; ++ky) {
#pragma unroll
            for (int kx = 0; kx < 3; ++kx) {
                float xv = s_p[(ty + ky) * 18 + tx + kx];
                const float* wr = wt3 + (ci * 9 + ky * 3 + kx) * 64;
#pragma unroll
                for (int o = 0; o < 64; ++o) acc[o] += xv * wr[o];
            }
        }
    }

    if (x < WW && y < HH) {
        int p = y * WW + x;
        const float* sb = skip + (size_t)bb * 64 * HWP + p;
        float* ob = out + (size_t)bb * 64 * HWP + p;
#pragma unroll
        for (int o = 0; o < 64; ++o) ob[(size_t)o * HWP] = acc[o] + sb[(size_t)o * HWP];
    }
}

extern "C" void kernel_launch(void* const* d_in, const int* in_sizes, int n_in,
                              void* d_out, int out_size, void* d_ws, size_t ws_size,
                              hipStream_t stream)
{
    const float* x_in      = (const float*)d_in[0];
    const float* ln_proj_w = (const float*)d_in[1];
    const float* ln_proj_b = (const float*)d_in[2];
    const float* proj_p_w  = (const float*)d_in[3];
    const float* proj_p_b  = (const float*)d_in[4];
    const float* proj_d_w  = (const float*)d_in[5];
    const float* proj_d_b  = (const float*)d_in[6];
    const float* proj_a_w  = (const float*)d_in[7];
    const float* proj_a_b  = (const float*)d_in[8];
    const float* ln_attn_w = (const float*)d_in[9];
    const float* ln_attn_b = (const float*)d_in[10];
    const float* qkv_w     = (const float*)d_in[11];
    const float* qkv_b     = (const float*)d_in[12];
    const float* attn_o_w  = (const float*)d_in[13];
    const float* attn_o_b  = (const float*)d_in[14];
    const float* rpb       = (const float*)d_in[15];
    const float* dwcp1_w   = (const float*)d_in[16];
    const float* dwcp1_b   = (const float*)d_in[17];
    const float* dwcp2_w   = (const float*)d_in[18];
    const float* dwcp2_b   = (const float*)d_in[19];
    const float* pconv_w   = (const float*)d_in[20];
    const float* pconv_b   = (const float*)d_in[21];
    const float* ffn_p_w   = (const float*)d_in[22];
    const float* ffn_p_b   = (const float*)d_in[23];
    const float* ffn_d_w   = (const float*)d_in[24];
    const float* ffn_d_b   = (const float*)d_in[25];
    const float* ffn_a_w   = (const float*)d_in[26];
    const float* ffn_a_b   = (const float*)d_in[27];
    const float* ln_out_w  = (const float*)d_in[28];
    const float* ln_out_b  = (const float*)d_in[29];
    const float* conv_o_w  = (const float*)d_in[30];
    const float* conv_o_b  = (const float*)d_in[31];
    const float* plk       = (const float*)d_in[32];

    float* X  = (float*)d_out;                 // running x, 4*64*40000
    float* ws = (float*)d_ws;
    float* A  = ws;                            // 10.24M floats
    float* R1 = ws + 10240000;                 // 20.48M floats (up to 128ch)
    float* R2 = ws + 30720000;                 // 2.56M floats (16ch)
    float* LKT = ws + 33280000;                // 43264
    float* GM = LKT + 43264;                   // 64
    float* DK = GM + 64;                       // 576
    float* WT = DK + 576;                      // 86016

    dim3 b256(256);
    dim3 gLN(157, 4);
    dim3 gT(13, 13, 4);

    // weight prep
    prep_kernel<<<dim3(336), b256, 0, stream>>>(proj_p_w, attn_o_w, ffn_p_w, proj_a_w,
                                                ffn_a_w, pconv_w, conv_o_w, WT);
    geo_kernel<<<dim3(169), b256, 0, stream>>>(plk, LKT);

    // x = LN(x); x = conv_ffn(x) [proj]
    ln_kernel<<<gLN, b256, 0, stream>>>(x_in, ln_proj_w, ln_proj_b, A);
    conv1x1_kernel<<<dim3(40, 8, 4), b256, 0, stream>>>(A, WT + 0, proj_p_b, R1, 64, 128, 1, 0);
    dwproj_kernel<<<gT, b256, 0, stream>>>(R1, proj_d_w, proj_d_b, WT + 22528, proj_a_b, X, 128);

    // x = x + window_attention(LN(x))
    ln_kernel<<<gLN, b256, 0, stream>>>(X, ln_attn_w, ln_attn_b, A);
    winattn_kernel<<<dim3(400, 8, 4), dim3(128), 0, stream>>>(A, qkv_w, qkv_b, rpb, R1);
    conv1x1_kernel<<<dim3(40, 4, 4), b256, 0, stream>>>(R1, WT + 8192, attn_o_b, X, 64, 64, 0, 1);

    for (int i = 0; i < 2; ++i) {
        // y = conv_ffn(x)
        conv1x1_kernel<<<dim3(40, 5, 4), b256, 0, stream>>>(X, WT + 12288 + i * 5120, ffn_p_b + i * 80, R1, 64, 80, 1, 0);
        dwproj_kernel<<<gT, b256, 0, stream>>>(R1, ffn_d_w + i * 720, ffn_d_b + i * 80,
                                               WT + 30720 + i * 5120, ffn_a_b + i * 64, A, 80);
        // y = conv_attention(y, lk)
        gmean_kernel<<<dim3(64), b256, 0, stream>>>(A, GM);
        dynk_kernel<<<dim3(4), dim3(192), 0, stream>>>(GM, dwcp1_w + i * 128, dwcp1_b + i * 8,
                                                       dwcp2_w + i * 1152, dwcp2_b + i * 144, DK);
        lkconv_kernel<<<gT, b256, 0, stream>>>(A, LKT, DK, R2);
        // y = pconv_aggr(concat(x1, x2)); x += y
        pconv_add_kernel<<<dim3(40, 4, 4), b256, 0, stream>>>(R2, A, WT + 40960 + i * 4096, pconv_b + i * 64, X);
    }

    // x = conv3x3(LN(x)) + skip
    ln_kernel<<<gLN, b256, 0, stream>>>(X, ln_out_w, ln_out_b, A);
    conv3_skip_kernel<<<gT, b256, 0, stream>>>(A, WT + 49152, conv_o_b, x_in, X);
}

// Round 3
// 1849.300 us; speedup vs baseline: 1.9695x; 1.0540x over previous
//
#include <hip/hip_runtime.h>
#include <math.h>

#define HH 200
#define WW 200
#define HWP 40000
#define NP4 10000
#define BB 4

__device__ __forceinline__ float gelu_f(float x) {
    return 0.5f * x * (1.0f + erff(x * 0.7071067811865475f));
}

// ---------------- weight prep: transposes so conv kernels use scalar (SGPR) weight loads ----
// wt layout offsets (floats):
//  0      wtP   (64,128)   proj_p
//  8192   wtAO  (64,64)    attn_out
//  12288  wtFP0 (64,80)    ffn_p[0]
//  17408  wtFP1 (64,80)    ffn_p[1]
//  22528  wtPA  (128,64)   proj_a
//  30720  wtFA0 (80,64)    ffn_a[0]
//  35840  wtFA1 (80,64)    ffn_a[1]
//  40960  wtPC0 (64,64)    pconv[0]
//  45056  wtPC1 (64,64)    pconv[1]
//  49152  wt3   (64,9,64)  conv_out  [ci][tap][co]
//  86016  wtQKV (64,192)   qkv
__device__ __forceinline__ void tr_w(const float* __restrict__ w, float* __restrict__ wt,
                                     int Co, int Ci, int idx) {
    int o = idx / Ci, c = idx - o * Ci;
    wt[c * Co + o] = w[idx];
}

__global__ __launch_bounds__(256) void prep_kernel(
    const float* __restrict__ pp, const float* __restrict__ ao,
    const float* __restrict__ fp, const float* __restrict__ pa,
    const float* __restrict__ fa, const float* __restrict__ pc,
    const float* __restrict__ co3, const float* __restrict__ qkvw,
    float* __restrict__ wt)
{
    int i = blockIdx.x * 256 + threadIdx.x;
    if (i < 8192) { tr_w(pp, wt + 0, 128, 64, i); return; } i -= 8192;
    if (i < 4096) { tr_w(ao, wt + 8192, 64, 64, i); return; } i -= 4096;
    if (i < 5120) { tr_w(fp, wt + 12288, 80, 64, i); return; } i -= 5120;
    if (i < 5120) { tr_w(fp + 5120, wt + 17408, 80, 64, i); return; } i -= 5120;
    if (i < 8192) { tr_w(pa, wt + 22528, 64, 128, i); return; } i -= 8192;
    if (i < 5120) { tr_w(fa, wt + 30720, 64, 80, i); return; } i -= 5120;
    if (i < 5120) { tr_w(fa + 5120, wt + 35840, 64, 80, i); return; } i -= 5120;
    if (i < 4096) { tr_w(pc, wt + 40960, 64, 64, i); return; } i -= 4096;
    if (i < 4096) { tr_w(pc + 4096, wt + 45056, 64, 64, i); return; } i -= 4096;
    if (i < 36864) {
        int o = i / 576; int r = i - o * 576; int c = r / 9; int t = r - c * 9;
        wt[49152 + (c * 9 + t) * 64 + o] = co3[i];
        return;
    } i -= 36864;
    if (i < 12288) { tr_w(qkvw, wt + 86016, 192, 64, i); return; }
}

// ---------------- LayerNorm over 64 channels ----------------
__global__ __launch_bounds__(256) void ln_kernel(
    const float* __restrict__ in, const float* __restrict__ w,
    const float* __restrict__ b, float* __restrict__ out)
{
    int p = blockIdx.x * 256 + threadIdx.x;
    int bb = blockIdx.y;
    if (p >= HWP) return;
    const float* ib = in + (size_t)bb * 64 * HWP + p;
    float v[64];
    float mu = 0.f;
#pragma unroll
    for (int c = 0; c < 64; ++c) { v[c] = ib[(size_t)c * HWP]; mu += v[c]; }
    mu *= (1.f / 64.f);
    float var = 0.f;
#pragma unroll
    for (int c = 0; c < 64; ++c) { float d = v[c] - mu; var += d * d; }
    var *= (1.f / 64.f);
    float r = rsqrtf(var + 1e-6f);
    float* ob = out + (size_t)bb * 64 * HWP + p;
#pragma unroll
    for (int c = 0; c < 64; ++c) ob[(size_t)c * HWP] = (v[c] - mu) * r * w[c] + b[c];
}

// ---------------- 1x1 conv: float4 pixels, 16 outputs/thread, scalar weights ----------------
__global__ __launch_bounds__(256) void conv1x1_kernel(
    const float* __restrict__ in, const float* __restrict__ wt,  // (Ci,Co)
    const float* __restrict__ bias, float* __restrict__ out,
    int Ci, int Co, int do_gelu, int do_add)
{
    int p4 = blockIdx.x * 256 + threadIdx.x;
    int o0 = blockIdx.y * 16;
    int bb = blockIdx.z;
    if (p4 >= NP4) return;
    float4 acc[16];
#pragma unroll
    for (int j = 0; j < 16; ++j) {
        float bv = bias[o0 + j];
        acc[j] = make_float4(bv, bv, bv, bv);
    }
    const float4* ib = (const float4*)(in + (size_t)bb * Ci * HWP) + p4;
    for (int c = 0; c < Ci; ++c) {
        float4 xv = ib[(size_t)c * NP4];
        const float* wr = wt + c * Co + o0;
#pragma unroll
        for (int j = 0; j < 16; ++j) {
            float w = wr[j];
            acc[j].x += xv.x * w; acc[j].y += xv.y * w;
            acc[j].z += xv.z * w; acc[j].w += xv.w * w;
        }
    }
    float4* ob = (float4*)(out + ((size_t)bb * Co + o0) * HWP) + p4;
#pragma unroll
    for (int j = 0; j < 16; ++j) {
        float4 r = acc[j];
        if (do_gelu) {
            r.x = gelu_f(r.x); r.y = gelu_f(r.y); r.z = gelu_f(r.z); r.w = gelu_f(r.w);
        }
        if (do_add) {
            float4 old = ob[(size_t)j * NP4];
            r.x += old.x; r.y += old.y; r.z += old.z; r.w += old.w;
        }
        ob[(size_t)j * NP4] = r;
    }
}

// ------- fused: gelu(dwconv3x3(in)) + in, then 1x1 proj (Ci -> 64), LDS-tiled -------
__global__ __launch_bounds__(256) void dwproj_kernel(
    const float* __restrict__ in,   // (B,Ci,H,W)
    const float* __restrict__ dw,   // (Ci,9)
    const float* __restrict__ db,   // (Ci)
    const float* __restrict__ awt,  // (Ci,64) transposed
    const float* __restrict__ ab,   // (64)
    float* __restrict__ out,        // (B,64,H,W)
    int Ci)
{
    __shared__ float s_p[18 * 18];
    int tid = threadIdx.x;
    int tx = tid & 15, ty = tid >> 4;
    int x0 = blockIdx.x * 16, y0 = blockIdx.y * 16;
    int bb = blockIdx.z;
    int x = x0 + tx, y = y0 + ty;

    float acc[64];
#pragma unroll
    for (int o = 0; o < 64; ++o) acc[o] = ab[o];

    const float* ibase = in + (size_t)bb * Ci * HWP;
    for (int ci = 0; ci < Ci; ++ci) {
        __syncthreads();
        const float* cb = ibase + (size_t)ci * HWP;
        for (int i = tid; i < 18 * 18; i += 256) {
            int py = i / 18, px = i - py * 18;
            int yy = y0 + py - 1, xx = x0 + px - 1;
            float v = 0.f;
            if ((unsigned)yy < HH && (unsigned)xx < WW) v = cb[yy * WW + xx];
            s_p[i] = v;
        }
        __syncthreads();
        float s = db[ci];
#pragma unroll
        for (int ky = 0; ky < 3; ++ky)
#pragma unroll
            for (int kx = 0; kx < 3; ++kx)
                s += s_p[(ty + ky) * 18 + tx + kx] * dw[ci * 9 + ky * 3 + kx];
        float v = gelu_f(s) + s_p[(ty + 1) * 18 + tx + 1];
        const float* wr = awt + ci * 64;
#pragma unroll
        for (int o = 0; o < 64; ++o) acc[o] += v * wr[o];
    }

    if (x < WW && y < HH) {
        int p = y * WW + x;
        float* ob = out + (size_t)bb * 64 * HWP + p;
#pragma unroll
        for (int o = 0; o < 64; ++o) ob[(size_t)o * HWP] = acc[o];
    }
}

// ---------------- attention v2: qkv precomputed; one block = (window, head) ----------------
__global__ __launch_bounds__(128) void winattn2_kernel(
    const float* __restrict__ qkv,  // (B,192,H,W)
    const float* __restrict__ rpb,  // (8,361)
    float* __restrict__ out)        // (B,64,H,W)
{
    __shared__ __align__(16) float s_k[100][8];
    __shared__ __align__(16) float s_v[100][8];
    __shared__ float s_b[361];

    int head = blockIdx.y, bb = blockIdx.z;
    int wy = blockIdx.x / 20, wx = blockIdx.x - wy * 20;
    int tid = threadIdx.x;

    for (int i = tid; i < 361; i += 128) s_b[i] = rpb[head * 361 + i];

    int ty = tid / 10, tx = tid - ty * 10;
    float q[8];
    if (tid < 100) {
        int y = wy * 10 + ty, x = wx * 10 + tx;
        int gp = y * WW + x;
        const float* qb = qkv + ((size_t)bb * 192 + head * 8) * HWP + gp;
        const float* kb = qb + (size_t)64 * HWP;
        const float* vb = qb + (size_t)128 * HWP;
#pragma unroll
        for (int cc = 0; cc < 8; ++cc) q[cc] = qb[(size_t)cc * HWP];
        float4 t0, t1;
        t0.x = kb[0];            t0.y = kb[(size_t)1 * HWP];
        t0.z = kb[(size_t)2 * HWP]; t0.w = kb[(size_t)3 * HWP];
        t1.x = kb[(size_t)4 * HWP]; t1.y = kb[(size_t)5 * HWP];
        t1.z = kb[(size_t)6 * HWP]; t1.w = kb[(size_t)7 * HWP];
        *(float4*)(&s_k[tid][0]) = t0;
        *(float4*)(&s_k[tid][4]) = t1;
        t0.x = vb[0];            t0.y = vb[(size_t)1 * HWP];
        t0.z = vb[(size_t)2 * HWP]; t0.w = vb[(size_t)3 * HWP];
        t1.x = vb[(size_t)4 * HWP]; t1.y = vb[(size_t)5 * HWP];
        t1.z = vb[(size_t)6 * HWP]; t1.w = vb[(size_t)7 * HWP];
        *(float4*)(&s_v[tid][0]) = t0;
        *(float4*)(&s_v[tid][4]) = t1;
    }
    __syncthreads();

    if (tid < 100) {
        const float scale = 0.3535533905932738f; // 1/sqrt(8)
        const float4* k4 = (const float4*)s_k;
        const float4* v4 = (const float4*)s_v;
        float m = -1e30f;
        {
            int ky = 0, kx = 0;
            for (int kk = 0; kk < 100; ++kk) {
                float4 ka = k4[kk * 2], kb = k4[kk * 2 + 1];
                float s = q[0] * ka.x + q[1] * ka.y + q[2] * ka.z + q[3] * ka.w
                        + q[4] * kb.x + q[5] * kb.y + q[6] * kb.z + q[7] * kb.w;
                s = s * scale + s_b[(ky - ty + 9) * 19 + (kx - tx + 9)];
                m = fmaxf(m, s);
                if (++kx == 10) { kx = 0; ++ky; }
            }
        }
        float l = 0.f;
        float o[8];
#pragma unroll
        for (int cc = 0; cc < 8; ++cc) o[cc] = 0.f;
        {
            int ky = 0, kx = 0;
            for (int kk = 0; kk < 100; ++kk) {
                float4 ka = k4[kk * 2], kb = k4[kk * 2 + 1];
                float s = q[0] * ka.x + q[1] * ka.y + q[2] * ka.z + q[3] * ka.w
                        + q[4] * kb.x + q[5] * kb.y + q[6] * kb.z + q[7] * kb.w;
                s = s * scale + s_b[(ky - ty + 9) * 19 + (kx - tx + 9)];
                float e = __expf(s - m);
                l += e;
                float4 va = v4[kk * 2], vb = v4[kk * 2 + 1];
                o[0] += e * va.x; o[1] += e * va.y; o[2] += e * va.z; o[3] += e * va.w;
                o[4] += e * vb.x; o[5] += e * vb.y; o[6] += e * vb.z; o[7] += e * vb.w;
                if (++kx == 10) { kx = 0; ++ky; }
            }
        }
        float rl = 1.f / l;
        int y = wy * 10 + ty, x = wx * 10 + tx;
        float* ob = out + ((size_t)bb * 64 + head * 8) * HWP + y * WW + x;
#pragma unroll
        for (int cc = 0; cc < 8; ++cc) ob[(size_t)cc * HWP] = o[cc] * rl;
    }
}

// ---------------- attention v1 (fallback, fused qkv): one block = (window, head) ----------------
__global__ __launch_bounds__(128) void winattn_kernel(
    const float* __restrict__ xin, const float* __restrict__ qkvw,
    const float* __restrict__ qkvb, const float* __restrict__ rpb,
    float* __restrict__ out)
{
    __shared__ __align__(16) float s_wq[8][64];
    __shared__ __align__(16) float s_wk[8][64];
    __shared__ __align__(16) float s_wv[8][64];
    __shared__ __align__(16) float s_k[100][8];
    __shared__ __align__(16) float s_v[100][8];
    __shared__ float s_b[361];

    int head = blockIdx.y, bb = blockIdx.z;
    int wy = blockIdx.x / 20, wx = blockIdx.x - wy * 20;
    int tid = threadIdx.x;

    for (int i = tid; i < 8 * 64; i += 128) {
        (&s_wq[0][0])[i] = qkvw[(head * 8) * 64 + i];
        (&s_wk[0][0])[i] = qkvw[(64 + head * 8) * 64 + i];
        (&s_wv[0][0])[i] = qkvw[(128 + head * 8) * 64 + i];
    }
    for (int i = tid; i < 361; i += 128) s_b[i] = rpb[head * 361 + i];
    __syncthreads();

    float q[8];
    int ty = tid / 10, tx = tid - ty * 10;
    if (tid < 100) {
        int y = wy * 10 + ty, x = wx * 10 + tx;
        const float* xb = xin + (size_t)bb * 64 * HWP + y * WW + x;
        float xr[64];
#pragma unroll
        for (int c = 0; c < 64; ++c) xr[c] = xb[(size_t)c * HWP];
#pragma unroll
        for (int cc = 0; cc < 8; ++cc) {
            float aq = qkvb[head * 8 + cc];
            float ak = qkvb[64 + head * 8 + cc];
            float av = qkvb[128 + head * 8 + cc];
#pragma unroll
            for (int c = 0; c < 64; ++c) {
                float xv = xr[c];
                aq += xv * s_wq[cc][c];
                ak += xv * s_wk[cc][c];
                av += xv * s_wv[cc][c];
            }
            q[cc] = aq;
            s_k[tid][cc] = ak;
            s_v[tid][cc] = av;
        }
    }
    __syncthreads();

    if (tid < 100) {
        const float scale = 0.3535533905932738f;
        const float4* k4 = (const float4*)s_k;
        const float4* v4 = (const float4*)s_v;
        float m = -1e30f;
        {
            int ky = 0, kx = 0;
            for (int kk = 0; kk < 100; ++kk) {
                float4 ka = k4[kk * 2], kb = k4[kk * 2 + 1];
                float s = q[0] * ka.x + q[1] * ka.y + q[2] * ka.z + q[3] * ka.w
                        + q[4] * kb.x + q[5] * kb.y + q[6] * kb.z + q[7] * kb.w;
                s = s * scale + s_b[(ky - ty + 9) * 19 + (kx - tx + 9)];
                m = fmaxf(m, s);
                if (++kx == 10) { kx = 0; ++ky; }
            }
        }
        float l = 0.f;
        float o[8];
#pragma unroll
        for (int cc = 0; cc < 8; ++cc) o[cc] = 0.f;
        {
            int ky = 0, kx = 0;
            for (int kk = 0; kk < 100; ++kk) {
                float4 ka = k4[kk * 2], kb = k4[kk * 2 + 1];
                float s = q[0] * ka.x + q[1] * ka.y + q[2] * ka.z + q[3] * ka.w
                        + q[4] * kb.x + q[5] * kb.y + q[6] * kb.z + q[7] * kb.w;
                s = s * scale + s_b[(ky - ty + 9) * 19 + (kx - tx + 9)];
                float e = __expf(s - m);
                l += e;
                float4 va = v4[kk * 2], vb = v4[kk * 2 + 1];
                o[0] += e * va.x; o[1] += e * va.y; o[2] += e * va.z; o[3] += e * va.w;
                o[4] += e * vb.x; o[5] += e * vb.y; o[6] += e * vb.z; o[7] += e * vb.w;
                if (++kx == 10) { kx = 0; ++ky; }
            }
        }
        float rl = 1.f / l;
        int y = wy * 10 + ty, x = wx * 10 + tx;
        float* ob = out + ((size_t)bb * 64 + head * 8) * HWP + y * WW + x;
#pragma unroll
        for (int cc = 0; cc < 8; ++cc) ob[(size_t)cc * HWP] = o[cc] * rl;
    }
}

// ------- geometric ensemble of 13x13 filter -> transposed (ci,tap,co) layout -------
__global__ __launch_bounds__(256) void geo_kernel(
    const float* __restrict__ k, float* __restrict__ out)
{
    int i = blockIdx.x * 256 + threadIdx.x;
    if (i >= 16 * 16 * 169) return;
    int oc = i / 169;                 // co*16 + ci
    int co = oc >> 4, ci = oc & 15;
    int t = i - oc * 169;
    int y = t / 13, x = t - y * 13;
    const float* kb = k + oc * 169;
    float s = kb[y * 13 + x] + kb[y * 13 + (12 - x)] + kb[(12 - y) * 13 + x] + kb[(12 - y) * 13 + (12 - x)]
            + kb[(12 - x) * 13 + y] + kb[x * 13 + y] + kb[(12 - x) * 13 + (12 - y)] + kb[x * 13 + (12 - y)];
    out[(ci * 169 + t) * 16 + co] = s * 0.125f;
}

// ---------------- global mean over H,W of first-16 channels ----------------
__global__ __launch_bounds__(256) void gmean_kernel(
    const float* __restrict__ in, float* __restrict__ g)
{
    int bc = blockIdx.x;            // b*16 + c
    int bb = bc >> 4, c = bc & 15;
    const float* p = in + ((size_t)bb * 64 + c) * HWP;
    float s = 0.f;
    for (int i = threadIdx.x; i < HWP; i += 256) s += p[i];
#pragma unroll
    for (int off = 32; off > 0; off >>= 1) s += __shfl_down(s, off);
    __shared__ float red[4];
    int wave = threadIdx.x >> 6;
    if ((threadIdx.x & 63) == 0) red[wave] = s;
    __syncthreads();
    if (threadIdx.x == 0)
        g[bc] = (red[0] + red[1] + red[2] + red[3]) * (1.f / 40000.f);
}

// ---------------- tiny MLP: g -> gelu(W1 g) -> W2 -> dynamic 3x3 kernels ----------------
__global__ __launch_bounds__(192) void dynk_kernel(
    const float* __restrict__ g, const float* __restrict__ w1, const float* __restrict__ b1,
    const float* __restrict__ w2, const float* __restrict__ b2, float* __restrict__ dk)
{
    int bb = blockIdx.x;
    __shared__ float s_g2[8];
    int tid = threadIdx.x;
    if (tid < 8) {
        float a = b1[tid];
        for (int c = 0; c < 16; ++c) a += w1[tid * 16 + c] * g[bb * 16 + c];
        s_g2[tid] = gelu_f(a);
    }
    __syncthreads();
    if (tid < 144) {
        float a = b2[tid];
#pragma unroll
        for (int i = 0; i < 8; ++i) a += w2[tid * 8 + i] * s_g2[i];
        dk[bb * 144 + tid] = a;
    }
}

// ------- 13x13 conv (16->16, pad 6) + dynamic depthwise 3x3 (pad 1), no bias -------
__global__ __launch_bounds__(256) void lkconv_kernel(
    const float* __restrict__ in,   // (B,64,H,W) — channels 0..15 used
    const float* __restrict__ lkT,  // (16,169,16)
    const float* __restrict__ dk,   // (B,144)
    float* __restrict__ out)        // (B,16,H,W)
{
    __shared__ float s_p[28 * 28];
    int bb = blockIdx.z;
    int tid = threadIdx.x;
    int tx = tid & 15, ty = tid >> 4;
    int x0 = blockIdx.x * 16, y0 = blockIdx.y * 16;
    int x = x0 + tx, y = y0 + ty;
    float acc[16];
#pragma unroll
    for (int co = 0; co < 16; ++co) acc[co] = 0.f;

    for (int ci = 0; ci < 16; ++ci) {
        __syncthreads();
        const float* cb = in + ((size_t)bb * 64 + ci) * HWP;
        for (int i = tid; i < 28 * 28; i += 256) {
            int py = i / 28, px = i - py * 28;
            int yy = y0 + py - 6, xx = x0 + px - 6;
            float v = 0.f;
            if ((unsigned)yy < HH && (unsigned)xx < WW) v = cb[yy * WW + xx];
            s_p[i] = v;
        }
        __syncthreads();

        const float* wci = lkT + ci * 169 * 16;
        for (int ky = 0; ky < 13; ++ky) {
#pragma unroll
            for (int kx = 0; kx < 13; ++kx) {
                float xv = s_p[(ty + ky) * 28 + tx + kx];
                const float* wr = wci + (ky * 13 + kx) * 16;
#pragma unroll
                for (int co = 0; co < 16; ++co) acc[co] += xv * wr[co];
            }
        }
        float d = 0.f;
#pragma unroll
        for (int dy = 0; dy < 3; ++dy)
#pragma unroll
            for (int dx = 0; dx < 3; ++dx)
                d += s_p[(ty + 5 + dy) * 28 + tx + 5 + dx] * dk[bb * 144 + ci * 9 + dy * 3 + dx];
#pragma unroll
        for (int co = 0; co < 16; ++co) acc[co] += (co == ci) ? d : 0.f;
    }

    if (x < WW && y < HH) {
        int p = y * WW + x;
        float* ob = out + (size_t)bb * 16 * HWP + p;
#pragma unroll
        for (int co = 0; co < 16; ++co) ob[(size_t)co * HWP] = acc[co];
    }
}

// ------- 1x1 conv over concat(x1[0..15], y[16..63]) and add into xout -------
__global__ __launch_bounds__(256) void pconv_add_kernel(
    const float* __restrict__ x1, const float* __restrict__ yy,
    const float* __restrict__ wt, const float* __restrict__ bias,
    float* __restrict__ xout)
{
    int p4 = blockIdx.x * 256 + threadIdx.x;
    int o0 = blockIdx.y * 16;
    int bb = blockIdx.z;
    if (p4 >= NP4) return;
    float4 acc[16];
#pragma unroll
    for (int j = 0; j < 16; ++j) {
        float bv = bias[o0 + j];
        acc[j] = make_float4(bv, bv, bv, bv);
    }
    const float4* xb = (const float4*)(x1 + (size_t)bb * 16 * HWP) + p4;
    for (int c = 0; c < 16; ++c) {
        float4 xv = xb[(size_t)c * NP4];
        const float* wr = wt + c * 64 + o0;
#pragma unroll
        for (int j = 0; j < 16; ++j) {
            float w = wr[j];
            acc[j].x += xv.x * w; acc[j].y += xv.y * w;
            acc[j].z += xv.z * w; acc[j].w += xv.w * w;
        }
    }
    const float4* yb = (const float4*)(yy + ((size_t)bb * 64 + 16) * HWP) + p4;
    for (int c = 0; c < 48; ++c) {
        float4 xv = yb[(size_t)c * NP4];
        const float* wr = wt + (16 + c) * 64 + o0;
#pragma unroll
        for (int j = 0; j < 16; ++j) {
            float w = wr[j];
            acc[j].x += xv.x * w; acc[j].y += xv.y * w;
            acc[j].z += xv.z * w; acc[j].w += xv.w * w;
        }
    }
    float4* ob = (float4*)(xout + ((size_t)bb * 64 + o0) * HWP) + p4;
#pragma unroll
    for (int j = 0; j < 16; ++j) {
        float4 old = ob[(size_t)j * NP4];
        old.x += acc[j].x; old.y += acc[j].y; old.z += acc[j].z; old.w += acc[j].w;
        ob[(size_t)j * NP4] = old;
    }
}

// ---------------- final 3x3 conv (64->64, pad 1) + bias + skip, LDS-tiled ----------------
__global__ __launch_bounds__(256) void conv3_skip_kernel(
    const float* __restrict__ in, const float* __restrict__ wt3,
    const float* __restrict__ bias, const float* __restrict__ skip,
    float* __restrict__ out)
{
    __shared__ float s_p[18 * 18];
    int tid = threadIdx.x;
    int tx = tid & 15, ty = tid >> 4;
    int x0 = blockIdx.x * 16, y0 = blockIdx.y * 16;
    int bb = blockIdx.z;
    int x = x0 + tx, y = y0 + ty;

    float acc[64];
#pragma unroll
    for (int o = 0; o < 64; ++o) acc[o] = bias[o];

    const float* ibase = in + (size_t)bb * 64 * HWP;
    for (int ci = 0; ci < 64; ++ci) {
        __syncthreads();
        const float* cb = ibase + (size_t)ci * HWP;
        for (int i = tid; i < 18 * 18; i += 256) {
            int py = i / 18, px = i - py * 18;
            int yy = y0 + py - 1, xx = x0 + px - 1;
            float v = 0.f;
            if ((unsigned)yy < HH && (unsigned)xx < WW) v = cb[yy * WW + xx];
            s_p[i] = v;
        }
        __syncthreads();
#pragma unroll
        for (int ky = 0; ky < 3; ++ky) {
#pragma unroll
            for (int kx = 0; kx < 3; ++kx) {
                float xv = s_p[(ty + ky) * 18 + tx + kx];
                const float* wr = wt3 + (ci * 9 + ky * 3 + kx) * 64;
#pragma unroll
                for (int o = 0; o < 64; ++o) acc[o] += xv * wr[o];
            }
        }
    }

    if (x < WW && y < HH) {
        int p = y * WW + x;
        const float* sb = skip + (size_t)bb * 64 * HWP + p;
        float* ob = out + (size_t)bb * 64 * HWP + p;
#pragma unroll
        for (int o = 0; o < 64; ++o) ob[(size_t)o * HWP] = acc[o] + sb[(size_t)o * HWP];
    }
}

extern "C" void kernel_launch(void* const* d_in, const int* in_sizes, int n_in,
                              void* d_out, int out_size, void* d_ws, size_t ws_size,
                              hipStream_t stream)
{
    const float* x_in      = (const float*)d_in[0];
    const float* ln_proj_w = (const float*)d_in[1];
    const float* ln_proj_b = (const float*)d_in[2];
    const float* proj_p_w  = (const float*)d_in[3];
    const float* proj_p_b  = (const float*)d_in[4];
    const float* proj_d_w  = (const float*)d_in[5];
    const float* proj_d_b  = (const float*)d_in[6];
    const float* proj_a_w  = (const float*)d_in[7];
    const float* proj_a_b  = (const float*)d_in[8];
    const float* ln_attn_w = (const float*)d_in[9];
    const float* ln_attn_b = (const float*)d_in[10];
    const float* qkv_w     = (const float*)d_in[11];
    const float* qkv_b     = (const float*)d_in[12];
    const float* attn_o_w  = (const float*)d_in[13];
    const float* attn_o_b  = (const float*)d_in[14];
    const float* rpb       = (const float*)d_in[15];
    const float* dwcp1_w   = (const float*)d_in[16];
    const float* dwcp1_b   = (const float*)d_in[17];
    const float* dwcp2_w   = (const float*)d_in[18];
    const float* dwcp2_b   = (const float*)d_in[19];
    const float* pconv_w   = (const float*)d_in[20];
    const float* pconv_b   = (const float*)d_in[21];
    const float* ffn_p_w   = (const float*)d_in[22];
    const float* ffn_p_b   = (const float*)d_in[23];
    const float* ffn_d_w   = (const float*)d_in[24];
    const float* ffn_d_b   = (const float*)d_in[25];
    const float* ffn_a_w   = (const float*)d_in[26];
    const float* ffn_a_b   = (const float*)d_in[27];
    const float* ln_out_w  = (const float*)d_in[28];
    const float* ln_out_b  = (const float*)d_in[29];
    const float* conv_o_w  = (const float*)d_in[30];
    const float* conv_o_b  = (const float*)d_in[31];
    const float* plk       = (const float*)d_in[32];

    float* X  = (float*)d_out;
    float* ws = (float*)d_ws;

    // big path needs A(10.24M) + QKV(30.72M) + R2(2.56M) + tables ≈ 43.67M floats
    bool big = ws_size >= (size_t)43700000 * 4;

    float* A   = ws;                                  // 10.24M floats
    float* QKV = ws + 10240000;                       // 30.72M floats (big path; overlaps R1)
    float* R1  = ws + 10240000;                       // 20.48M floats
    float* R2  = big ? ws + 40960000 : ws + 30720000; // 2.56M floats
    float* LKT = R2 + 2560000;                        // 43264
    float* GM  = LKT + 43264;                         // 64
    float* DK  = GM + 64;                             // 576
    float* WT  = DK + 576;                            // 98304

    dim3 b256(256);
    dim3 gLN(157, 4);
    dim3 gT(13, 13, 4);

    prep_kernel<<<dim3(384), b256, 0, stream>>>(proj_p_w, attn_o_w, ffn_p_w, proj_a_w,
                                                ffn_a_w, pconv_w, conv_o_w, qkv_w, WT);
    geo_kernel<<<dim3(169), b256, 0, stream>>>(plk, LKT);

    // x = LN(x); x = conv_ffn(x) [proj]
    ln_kernel<<<gLN, b256, 0, stream>>>(x_in, ln_proj_w, ln_proj_b, A);
    conv1x1_kernel<<<dim3(40, 8, 4), b256, 0, stream>>>(A, WT + 0, proj_p_b, R1, 64, 128, 1, 0);
    dwproj_kernel<<<gT, b256, 0, stream>>>(R1, proj_d_w, proj_d_b, WT + 22528, proj_a_b, X, 128);

    // x = x + window_attention(LN(x))
    ln_kernel<<<gLN, b256, 0, stream>>>(X, ln_attn_w, ln_attn_b, A);
    if (big) {
        conv1x1_kernel<<<dim3(40, 12, 4), b256, 0, stream>>>(A, WT + 86016, qkv_b, QKV, 64, 192, 0, 0);
        winattn2_kernel<<<dim3(400, 8, 4), dim3(128), 0, stream>>>(QKV, rpb, A);
        conv1x1_kernel<<<dim3(40, 4, 4), b256, 0, stream>>>(A, WT + 8192, attn_o_b, X, 64, 64, 0, 1);
    } else {
        winattn_kernel<<<dim3(400, 8, 4), dim3(128), 0, stream>>>(A, qkv_w, qkv_b, rpb, R1);
        conv1x1_kernel<<<dim3(40, 4, 4), b256, 0, stream>>>(R1, WT + 8192, attn_o_b, X, 64, 64, 0, 1);
    }

    for (int i = 0; i < 2; ++i) {
        conv1x1_kernel<<<dim3(40, 5, 4), b256, 0, stream>>>(X, WT + 12288 + i * 5120, ffn_p_b + i * 80, R1, 64, 80, 1, 0);
        dwproj_kernel<<<gT, b256, 0, stream>>>(R1, ffn_d_w + i * 720, ffn_d_b + i * 80,
                                               WT + 30720 + i * 5120, ffn_a_b + i * 64, A, 80);
        gmean_kernel<<<dim3(64), b256, 0, stream>>>(A, GM);
        dynk_kernel<<<dim3(4), dim3(192), 0, stream>>>(GM, dwcp1_w + i * 128, dwcp1_b + i * 8,
                                                       dwcp2_w + i * 1152, dwcp2_b + i * 144, DK);
        lkconv_kernel<<<gT, b256, 0, stream>>>(A, LKT, DK, R2);
        pconv_add_kernel<<<dim3(40, 4, 4), b256, 0, stream>>>(R2, A, WT + 40960 + i * 4096, pconv_b + i * 64, X);
    }

    ln_kernel<<<gLN, b256, 0, stream>>>(X, ln_out_w, ln_out_b, A);
    conv3_skip_kernel<<<gT, b256, 0, stream>>>(A, WT + 49152, conv_o_b, x_in, X);
}

// Round 4
// 1607.942 us; speedup vs baseline: 2.2651x; 1.1501x over previous
//
#include <hip/hip_runtime.h>
#include <math.h>

#define HH 200
#define WW 200
#define HWP 40000
#define NP4 10000
#define BB 4

__device__ __forceinline__ float gelu_f(float x) {
    return 0.5f * x * (1.0f + erff(x * 0.7071067811865475f));
}

// ---------------- weight prep (transposes for scalar weight loads) ----------------
// wt layout offsets (floats):
//  0      wtP   (64,128)   proj_p
//  8192   wtAO  (64,64)    attn_out
//  12288  wtFP0 (64,80)    ffn_p[0]
//  17408  wtFP1 (64,80)    ffn_p[1]
//  22528  wtPA  (128,64)   proj_a
//  30720  wtFA0 (80,64)    ffn_a[0]
//  35840  wtFA1 (80,64)    ffn_a[1]
//  40960  wtPC0 (64,64)    pconv[0]
//  45056  wtPC1 (64,64)    pconv[1]
//  49152  wt3   (64,9,64)  conv_out  [ci][tap][co]
//  86016  wtQKV (64,192)   qkv
__device__ __forceinline__ void tr_w(const float* __restrict__ w, float* __restrict__ wt,
                                     int Co, int Ci, int idx) {
    int o = idx / Ci, c = idx - o * Ci;
    wt[c * Co + o] = w[idx];
}

__global__ __launch_bounds__(256) void prep_kernel(
    const float* __restrict__ pp, const float* __restrict__ ao,
    const float* __restrict__ fp, const float* __restrict__ pa,
    const float* __restrict__ fa, const float* __restrict__ pc,
    const float* __restrict__ co3, const float* __restrict__ qkvw,
    float* __restrict__ wt)
{
    int i = blockIdx.x * 256 + threadIdx.x;
    if (i < 8192) { tr_w(pp, wt + 0, 128, 64, i); return; } i -= 8192;
    if (i < 4096) { tr_w(ao, wt + 8192, 64, 64, i); return; } i -= 4096;
    if (i < 5120) { tr_w(fp, wt + 12288, 80, 64, i); return; } i -= 5120;
    if (i < 5120) { tr_w(fp + 5120, wt + 17408, 80, 64, i); return; } i -= 5120;
    if (i < 8192) { tr_w(pa, wt + 22528, 64, 128, i); return; } i -= 8192;
    if (i < 5120) { tr_w(fa, wt + 30720, 64, 80, i); return; } i -= 5120;
    if (i < 5120) { tr_w(fa + 5120, wt + 35840, 64, 80, i); return; } i -= 5120;
    if (i < 4096) { tr_w(pc, wt + 40960, 64, 64, i); return; } i -= 4096;
    if (i < 4096) { tr_w(pc + 4096, wt + 45056, 64, 64, i); return; } i -= 4096;
    if (i < 36864) {
        int o = i / 576; int r = i - o * 576; int c = r / 9; int t = r - c * 9;
        wt[49152 + (c * 9 + t) * 64 + o] = co3[i];
        return;
    } i -= 36864;
    if (i < 12288) { tr_w(qkvw, wt + 86016, 192, 64, i); return; }
}

// ---------------- LayerNorm over 64 channels ----------------
__global__ __launch_bounds__(256, 2) void ln_kernel(
    const float* __restrict__ in, const float* __restrict__ w,
    const float* __restrict__ b, float* __restrict__ out)
{
    int p = blockIdx.x * 256 + threadIdx.x;
    int bb = blockIdx.y;
    if (p >= HWP) return;
    const float* ib = in + (size_t)bb * 64 * HWP + p;
    float v[64];
    float mu = 0.f;
#pragma unroll
    for (int c = 0; c < 64; ++c) { v[c] = ib[(size_t)c * HWP]; mu += v[c]; }
    mu *= (1.f / 64.f);
    float var = 0.f;
#pragma unroll
    for (int c = 0; c < 64; ++c) { float d = v[c] - mu; var += d * d; }
    var *= (1.f / 64.f);
    float r = rsqrtf(var + 1e-6f);
    float* ob = out + (size_t)bb * 64 * HWP + p;
#pragma unroll
    for (int c = 0; c < 64; ++c) ob[(size_t)c * HWP] = (v[c] - mu) * r * w[c] + b[c];
}

// ---------------- 1x1 conv: float4 pixels, 16 outputs/thread, scalar weights ----------------
__global__ __launch_bounds__(256, 2) void conv1x1_kernel(
    const float* __restrict__ in, const float* __restrict__ wt,  // (Ci,Co)
    const float* __restrict__ bias, float* __restrict__ out,
    int Ci, int Co, int do_gelu, int do_add)
{
    int p4 = blockIdx.x * 256 + threadIdx.x;
    int o0 = blockIdx.y * 16;
    int bb = blockIdx.z;
    if (p4 >= NP4) return;
    float4 acc[16];
#pragma unroll
    for (int j = 0; j < 16; ++j) {
        float bv = bias[o0 + j];
        acc[j] = make_float4(bv, bv, bv, bv);
    }
    const float4* ib = (const float4*)(in + (size_t)bb * Ci * HWP) + p4;
    for (int c = 0; c < Ci; ++c) {
        float4 xv = ib[(size_t)c * NP4];
        const float* wr = wt + c * Co + o0;
#pragma unroll
        for (int j = 0; j < 16; ++j) {
            float w = wr[j];
            acc[j].x += xv.x * w; acc[j].y += xv.y * w;
            acc[j].z += xv.z * w; acc[j].w += xv.w * w;
        }
    }
    float4* ob = (float4*)(out + ((size_t)bb * Co + o0) * HWP) + p4;
#pragma unroll
    for (int j = 0; j < 16; ++j) {
        float4 r = acc[j];
        if (do_gelu) {
            r.x = gelu_f(r.x); r.y = gelu_f(r.y); r.z = gelu_f(r.z); r.w = gelu_f(r.w);
        }
        if (do_add) {
            float4 old = ob[(size_t)j * NP4];
            r.x += old.x; r.y += old.y; r.z += old.z; r.w += old.w;
        }
        ob[(size_t)j * NP4] = r;
    }
}

// ------- fused: gelu(dwconv3x3(in)) + in, then 1x1 proj (Ci -> 64), 16-ci chunked LDS -------
__global__ __launch_bounds__(256, 2) void dwproj_kernel(
    const float* __restrict__ in,   // (B,Ci,H,W)
    const float* __restrict__ dw,   // (Ci,9)
    const float* __restrict__ db,   // (Ci)
    const float* __restrict__ awt,  // (Ci,64) transposed
    const float* __restrict__ ab,   // (64)
    float* __restrict__ out,        // (B,64,H,W)
    int Ci)
{
    __shared__ float s_p[16][324];  // 16 channels x 18x18
    int tid = threadIdx.x;
    int tx = tid & 15, ty = tid >> 4;
    int x0 = blockIdx.x * 16, y0 = blockIdx.y * 16;
    int bb = blockIdx.z;
    int x = x0 + tx, y = y0 + ty;

    float acc[64];
#pragma unroll
    for (int o = 0; o < 64; ++o) acc[o] = ab[o];

    const float* ibase = in + (size_t)bb * Ci * HWP;
    for (int c0 = 0; c0 < Ci; c0 += 16) {
        __syncthreads();
        for (int i = tid; i < 16 * 324; i += 256) {
            int ci = i / 324; int r = i - ci * 324;
            int py = r / 18, px = r - py * 18;
            int yy = y0 + py - 1, xx = x0 + px - 1;
            float v = 0.f;
            if ((unsigned)yy < HH && (unsigned)xx < WW)
                v = ibase[(size_t)(c0 + ci) * HWP + yy * WW + xx];
            s_p[ci][r] = v;
        }
        __syncthreads();
        for (int ci = 0; ci < 16; ++ci) {
            int c = c0 + ci;
            float s = db[c];
            const float* dwr = dw + c * 9;
#pragma unroll
            for (int ky = 0; ky < 3; ++ky)
#pragma unroll
                for (int kx = 0; kx < 3; ++kx)
                    s += s_p[ci][(ty + ky) * 18 + tx + kx] * dwr[ky * 3 + kx];
            float v = gelu_f(s) + s_p[ci][(ty + 1) * 18 + tx + 1];
            const float* wr = awt + c * 64;
#pragma unroll
            for (int o = 0; o < 64; ++o) acc[o] += v * wr[o];
        }
    }

    if (x < WW && y < HH) {
        int p = y * WW + x;
        float* ob = out + (size_t)bb * 64 * HWP + p;
#pragma unroll
        for (int o = 0; o < 64; ++o) ob[(size_t)o * HWP] = acc[o];
    }
}

// ---------------- attention v2: qkv precomputed; one block = (window, head) ----------------
__global__ __launch_bounds__(128) void winattn2_kernel(
    const float* __restrict__ qkv,  // (B,192,H,W)
    const float* __restrict__ rpb,  // (8,361)
    float* __restrict__ out)        // (B,64,H,W)
{
    __shared__ __align__(16) float s_k[100][8];
    __shared__ __align__(16) float s_v[100][8];
    __shared__ float s_b[361];

    int head = blockIdx.y, bb = blockIdx.z;
    int wy = blockIdx.x / 20, wx = blockIdx.x - wy * 20;
    int tid = threadIdx.x;

    for (int i = tid; i < 361; i += 128) s_b[i] = rpb[head * 361 + i];

    int ty = tid / 10, tx = tid - ty * 10;
    float q[8];
    if (tid < 100) {
        int y = wy * 10 + ty, x = wx * 10 + tx;
        int gp = y * WW + x;
        const float* qb = qkv + ((size_t)bb * 192 + head * 8) * HWP + gp;
        const float* kb = qb + (size_t)64 * HWP;
        const float* vb = qb + (size_t)128 * HWP;
#pragma unroll
        for (int cc = 0; cc < 8; ++cc) q[cc] = qb[(size_t)cc * HWP];
        float4 t0, t1;
        t0.x = kb[0];               t0.y = kb[(size_t)1 * HWP];
        t0.z = kb[(size_t)2 * HWP]; t0.w = kb[(size_t)3 * HWP];
        t1.x = kb[(size_t)4 * HWP]; t1.y = kb[(size_t)5 * HWP];
        t1.z = kb[(size_t)6 * HWP]; t1.w = kb[(size_t)7 * HWP];
        *(float4*)(&s_k[tid][0]) = t0;
        *(float4*)(&s_k[tid][4]) = t1;
        t0.x = vb[0];               t0.y = vb[(size_t)1 * HWP];
        t0.z = vb[(size_t)2 * HWP]; t0.w = vb[(size_t)3 * HWP];
        t1.x = vb[(size_t)4 * HWP]; t1.y = vb[(size_t)5 * HWP];
        t1.z = vb[(size_t)6 * HWP]; t1.w = vb[(size_t)7 * HWP];
        *(float4*)(&s_v[tid][0]) = t0;
        *(float4*)(&s_v[tid][4]) = t1;
    }
    __syncthreads();

    if (tid < 100) {
        const float scale = 0.3535533905932738f; // 1/sqrt(8)
        const float4* k4 = (const float4*)s_k;
        const float4* v4 = (const float4*)s_v;
        float m = -1e30f;
        {
            int ky = 0, kx = 0;
            for (int kk = 0; kk < 100; ++kk) {
                float4 ka = k4[kk * 2], kb = k4[kk * 2 + 1];
                float s = q[0] * ka.x + q[1] * ka.y + q[2] * ka.z + q[3] * ka.w
                        + q[4] * kb.x + q[5] * kb.y + q[6] * kb.z + q[7] * kb.w;
                s = s * scale + s_b[(ky - ty + 9) * 19 + (kx - tx + 9)];
                m = fmaxf(m, s);
                if (++kx == 10) { kx = 0; ++ky; }
            }
        }
        float l = 0.f;
        float o[8];
#pragma unroll
        for (int cc = 0; cc < 8; ++cc) o[cc] = 0.f;
        {
            int ky = 0, kx = 0;
            for (int kk = 0; kk < 100; ++kk) {
                float4 ka = k4[kk * 2], kb = k4[kk * 2 + 1];
                float s = q[0] * ka.x + q[1] * ka.y + q[2] * ka.z + q[3] * ka.w
                        + q[4] * kb.x + q[5] * kb.y + q[6] * kb.z + q[7] * kb.w;
                s = s * scale + s_b[(ky - ty + 9) * 19 + (kx - tx + 9)];
                float e = __expf(s - m);
                l += e;
                float4 va = v4[kk * 2], vb = v4[kk * 2 + 1];
                o[0] += e * va.x; o[1] += e * va.y; o[2] += e * va.z; o[3] += e * va.w;
                o[4] += e * vb.x; o[5] += e * vb.y; o[6] += e * vb.z; o[7] += e * vb.w;
                if (++kx == 10) { kx = 0; ++ky; }
            }
        }
        float rl = 1.f / l;
        int y = wy * 10 + ty, x = wx * 10 + tx;
        float* ob = out + ((size_t)bb * 64 + head * 8) * HWP + y * WW + x;
#pragma unroll
        for (int cc = 0; cc < 8; ++cc) ob[(size_t)cc * HWP] = o[cc] * rl;
    }
}

// ---------------- attention v1 (fallback, fused qkv) ----------------
__global__ __launch_bounds__(128) void winattn_kernel(
    const float* __restrict__ xin, const float* __restrict__ qkvw,
    const float* __restrict__ qkvb, const float* __restrict__ rpb,
    float* __restrict__ out)
{
    __shared__ __align__(16) float s_wq[8][64];
    __shared__ __align__(16) float s_wk[8][64];
    __shared__ __align__(16) float s_wv[8][64];
    __shared__ __align__(16) float s_k[100][8];
    __shared__ __align__(16) float s_v[100][8];
    __shared__ float s_b[361];

    int head = blockIdx.y, bb = blockIdx.z;
    int wy = blockIdx.x / 20, wx = blockIdx.x - wy * 20;
    int tid = threadIdx.x;

    for (int i = tid; i < 8 * 64; i += 128) {
        (&s_wq[0][0])[i] = qkvw[(head * 8) * 64 + i];
        (&s_wk[0][0])[i] = qkvw[(64 + head * 8) * 64 + i];
        (&s_wv[0][0])[i] = qkvw[(128 + head * 8) * 64 + i];
    }
    for (int i = tid; i < 361; i += 128) s_b[i] = rpb[head * 361 + i];
    __syncthreads();

    float q[8];
    int ty = tid / 10, tx = tid - ty * 10;
    if (tid < 100) {
        int y = wy * 10 + ty, x = wx * 10 + tx;
        const float* xb = xin + (size_t)bb * 64 * HWP + y * WW + x;
        float xr[64];
#pragma unroll
        for (int c = 0; c < 64; ++c) xr[c] = xb[(size_t)c * HWP];
#pragma unroll
        for (int cc = 0; cc < 8; ++cc) {
            float aq = qkvb[head * 8 + cc];
            float ak = qkvb[64 + head * 8 + cc];
            float av = qkvb[128 + head * 8 + cc];
#pragma unroll
            for (int c = 0; c < 64; ++c) {
                float xv = xr[c];
                aq += xv * s_wq[cc][c];
                ak += xv * s_wk[cc][c];
                av += xv * s_wv[cc][c];
            }
            q[cc] = aq;
            s_k[tid][cc] = ak;
            s_v[tid][cc] = av;
        }
    }
    __syncthreads();

    if (tid < 100) {
        const float scale = 0.3535533905932738f;
        const float4* k4 = (const float4*)s_k;
        const float4* v4 = (const float4*)s_v;
        float m = -1e30f;
        {
            int ky = 0, kx = 0;
            for (int kk = 0; kk < 100; ++kk) {
                float4 ka = k4[kk * 2], kb = k4[kk * 2 + 1];
                float s = q[0] * ka.x + q[1] * ka.y + q[2] * ka.z + q[3] * ka.w
                        + q[4] * kb.x + q[5] * kb.y + q[6] * kb.z + q[7] * kb.w;
                s = s * scale + s_b[(ky - ty + 9) * 19 + (kx - tx + 9)];
                m = fmaxf(m, s);
                if (++kx == 10) { kx = 0; ++ky; }
            }
        }
        float l = 0.f;
        float o[8];
#pragma unroll
        for (int cc = 0; cc < 8; ++cc) o[cc] = 0.f;
        {
            int ky = 0, kx = 0;
            for (int kk = 0; kk < 100; ++kk) {
                float4 ka = k4[kk * 2], kb = k4[kk * 2 + 1];
                float s = q[0] * ka.x + q[1] * ka.y + q[2] * ka.z + q[3] * ka.w
                        + q[4] * kb.x + q[5] * kb.y + q[6] * kb.z + q[7] * kb.w;
                s = s * scale + s_b[(ky - ty + 9) * 19 + (kx - tx + 9)];
                float e = __expf(s - m);
                l += e;
                float4 va = v4[kk * 2], vb = v4[kk * 2 + 1];
                o[0] += e * va.x; o[1] += e * va.y; o[2] += e * va.z; o[3] += e * va.w;
                o[4] += e * vb.x; o[5] += e * vb.y; o[6] += e * vb.z; o[7] += e * vb.w;
                if (++kx == 10) { kx = 0; ++ky; }
            }
        }
        float rl = 1.f / l;
        int y = wy * 10 + ty, x = wx * 10 + tx;
        float* ob = out + ((size_t)bb * 64 + head * 8) * HWP + y * WW + x;
#pragma unroll
        for (int cc = 0; cc < 8; ++cc) ob[(size_t)cc * HWP] = o[cc] * rl;
    }
}

// ------- geometric ensemble of 13x13 filter -> transposed (ci,tap,co) layout -------
__global__ __launch_bounds__(256) void geo_kernel(
    const float* __restrict__ k, float* __restrict__ out)
{
    int i = blockIdx.x * 256 + threadIdx.x;
    if (i >= 16 * 16 * 169) return;
    int oc = i / 169;                 // co*16 + ci
    int co = oc >> 4, ci = oc & 15;
    int t = i - oc * 169;
    int y = t / 13, x = t - y * 13;
    const float* kb = k + oc * 169;
    float s = kb[y * 13 + x] + kb[y * 13 + (12 - x)] + kb[(12 - y) * 13 + x] + kb[(12 - y) * 13 + (12 - x)]
            + kb[(12 - x) * 13 + y] + kb[x * 13 + y] + kb[(12 - x) * 13 + (12 - y)] + kb[x * 13 + (12 - y)];
    out[(ci * 169 + t) * 16 + co] = s * 0.125f;
}

// ---------------- global mean over H,W of first-16 channels ----------------
__global__ __launch_bounds__(256) void gmean_kernel(
    const float* __restrict__ in, float* __restrict__ g)
{
    int bc = blockIdx.x;            // b*16 + c
    int bb = bc >> 4, c = bc & 15;
    const float* p = in + ((size_t)bb * 64 + c) * HWP;
    float s = 0.f;
    for (int i = threadIdx.x; i < HWP; i += 256) s += p[i];
#pragma unroll
    for (int off = 32; off > 0; off >>= 1) s += __shfl_down(s, off);
    __shared__ float red[4];
    int wave = threadIdx.x >> 6;
    if ((threadIdx.x & 63) == 0) red[wave] = s;
    __syncthreads();
    if (threadIdx.x == 0)
        g[bc] = (red[0] + red[1] + red[2] + red[3]) * (1.f / 40000.f);
}

// ---------------- tiny MLP -> dynamic 3x3 kernels ----------------
__global__ __launch_bounds__(192) void dynk_kernel(
    const float* __restrict__ g, const float* __restrict__ w1, const float* __restrict__ b1,
    const float* __restrict__ w2, const float* __restrict__ b2, float* __restrict__ dk)
{
    int bb = blockIdx.x;
    __shared__ float s_g2[8];
    int tid = threadIdx.x;
    if (tid < 8) {
        float a = b1[tid];
        for (int c = 0; c < 16; ++c) a += w1[tid * 16 + c] * g[bb * 16 + c];
        s_g2[tid] = gelu_f(a);
    }
    __syncthreads();
    if (tid < 144) {
        float a = b2[tid];
#pragma unroll
        for (int i = 0; i < 8; ++i) a += w2[tid * 8 + i] * s_g2[i];
        dk[bb * 144 + tid] = a;
    }
}

// ------- 13x13 conv (16->16, pad 6) + dynamic depthwise 3x3, all-16-ci LDS staged -------
__global__ __launch_bounds__(256, 2) void lkconv_kernel(
    const float* __restrict__ in,   // (B,64,H,W) — channels 0..15 used
    const float* __restrict__ lkT,  // (16,169,16)
    const float* __restrict__ dk,   // (B,144)
    float* __restrict__ out)        // (B,16,H,W)
{
    __shared__ float s_p[16][784];  // 16 channels x 28x28 = 50 KB
    int bb = blockIdx.z;
    int tid = threadIdx.x;
    int tx = tid & 15, ty = tid >> 4;
    int x0 = blockIdx.x * 16, y0 = blockIdx.y * 16;
    int x = x0 + tx, y = y0 + ty;

    const float* ibase = in + (size_t)bb * 64 * HWP;
    for (int i = tid; i < 16 * 784; i += 256) {
        int ci = i / 784; int r = i - ci * 784;
        int py = r / 28, px = r - py * 28;
        int yy = y0 + py - 6, xx = x0 + px - 6;
        float v = 0.f;
        if ((unsigned)yy < HH && (unsigned)xx < WW)
            v = ibase[(size_t)ci * HWP + yy * WW + xx];
        s_p[ci][r] = v;
    }
    __syncthreads();

    float acc[16];
#pragma unroll
    for (int co = 0; co < 16; ++co) acc[co] = 0.f;

    for (int ci = 0; ci < 16; ++ci) {
        const float* wci = lkT + ci * 169 * 16;
        for (int ky = 0; ky < 13; ++ky) {
#pragma unroll
            for (int kx = 0; kx < 13; ++kx) {
                float xv = s_p[ci][(ty + ky) * 28 + tx + kx];
                const float* wr = wci + (ky * 13 + kx) * 16;
#pragma unroll
                for (int co = 0; co < 16; ++co) acc[co] += xv * wr[co];
            }
        }
        float d = 0.f;
        const float* dkr = dk + bb * 144 + ci * 9;
#pragma unroll
        for (int dy = 0; dy < 3; ++dy)
#pragma unroll
            for (int dx = 0; dx < 3; ++dx)
                d += s_p[ci][(ty + 5 + dy) * 28 + tx + 5 + dx] * dkr[dy * 3 + dx];
#pragma unroll
        for (int co = 0; co < 16; ++co) acc[co] += (co == ci) ? d : 0.f;
    }

    if (x < WW && y < HH) {
        int p = y * WW + x;
        float* ob = out + (size_t)bb * 16 * HWP + p;
#pragma unroll
        for (int co = 0; co < 16; ++co) ob[(size_t)co * HWP] = acc[co];
    }
}

// ------- 1x1 conv over concat(x1[0..15], y[16..63]) and add into xout -------
__global__ __launch_bounds__(256, 2) void pconv_add_kernel(
    const float* __restrict__ x1, const float* __restrict__ yy,
    const float* __restrict__ wt, const float* __restrict__ bias,
    float* __restrict__ xout)
{
    int p4 = blockIdx.x * 256 + threadIdx.x;
    int o0 = blockIdx.y * 16;
    int bb = blockIdx.z;
    if (p4 >= NP4) return;
    float4 acc[16];
#pragma unroll
    for (int j = 0; j < 16; ++j) {
        float bv = bias[o0 + j];
        acc[j] = make_float4(bv, bv, bv, bv);
    }
    const float4* xb = (const float4*)(x1 + (size_t)bb * 16 * HWP) + p4;
    for (int c = 0; c < 16; ++c) {
        float4 xv = xb[(size_t)c * NP4];
        const float* wr = wt + c * 64 + o0;
#pragma unroll
        for (int j = 0; j < 16; ++j) {
            float w = wr[j];
            acc[j].x += xv.x * w; acc[j].y += xv.y * w;
            acc[j].z += xv.z * w; acc[j].w += xv.w * w;
        }
    }
    const float4* yb = (const float4*)(yy + ((size_t)bb * 64 + 16) * HWP) + p4;
    for (int c = 0; c < 48; ++c) {
        float4 xv = yb[(size_t)c * NP4];
        const float* wr = wt + (16 + c) * 64 + o0;
#pragma unroll
        for (int j = 0; j < 16; ++j) {
            float w = wr[j];
            acc[j].x += xv.x * w; acc[j].y += xv.y * w;
            acc[j].z += xv.z * w; acc[j].w += xv.w * w;
        }
    }
    float4* ob = (float4*)(xout + ((size_t)bb * 64 + o0) * HWP) + p4;
#pragma unroll
    for (int j = 0; j < 16; ++j) {
        float4 old = ob[(size_t)j * NP4];
        old.x += acc[j].x; old.y += acc[j].y; old.z += acc[j].z; old.w += acc[j].w;
        ob[(size_t)j * NP4] = old;
    }
}

// ---------------- final 3x3 conv (64->64) + bias + skip, 16-ci chunked LDS ----------------
__global__ __launch_bounds__(256, 2) void conv3_skip_kernel(
    const float* __restrict__ in, const float* __restrict__ wt3,  // (ci,tap,co)
    const float* __restrict__ bias, const float* __restrict__ skip,
    float* __restrict__ out)
{
    __shared__ float s_p[16][324];  // 16 channels x 18x18
    int tid = threadIdx.x;
    int tx = tid & 15, ty = tid >> 4;
    int x0 = blockIdx.x * 16, y0 = blockIdx.y * 16;
    int bb = blockIdx.z;
    int x = x0 + tx, y = y0 + ty;

    float acc[64];
#pragma unroll
    for (int o = 0; o < 64; ++o) acc[o] = bias[o];

    const float* ibase = in + (size_t)bb * 64 * HWP;
    for (int c0 = 0; c0 < 64; c0 += 16) {
        __syncthreads();
        for (int i = tid; i < 16 * 324; i += 256) {
            int ci = i / 324; int r = i - ci * 324;
            int py = r / 18, px = r - py * 18;
            int yy = y0 + py - 1, xx = x0 + px - 1;
            float v = 0.f;
            if ((unsigned)yy < HH && (unsigned)xx < WW)
                v = ibase[(size_t)(c0 + ci) * HWP + yy * WW + xx];
            s_p[ci][r] = v;
        }
        __syncthreads();
        for (int ci = 0; ci < 16; ++ci) {
            const float* wr0 = wt3 + (size_t)(c0 + ci) * 9 * 64;
#pragma unroll
            for (int ky = 0; ky < 3; ++ky) {
#pragma unroll
                for (int kx = 0; kx < 3; ++kx) {
                    float xv = s_p[ci][(ty + ky) * 18 + tx + kx];
                    const float* wr = wr0 + (ky * 3 + kx) * 64;
#pragma unroll
                    for (int o = 0; o < 64; ++o) acc[o] += xv * wr[o];
                }
            }
        }
    }

    if (x < WW && y < HH) {
        int p = y * WW + x;
        const float* sb = skip + (size_t)bb * 64 * HWP + p;
        float* ob = out + (size_t)bb * 64 * HWP + p;
#pragma unroll
        for (int o = 0; o < 64; ++o) ob[(size_t)o * HWP] = acc[o] + sb[(size_t)o * HWP];
    }
}

extern "C" void kernel_launch(void* const* d_in, const int* in_sizes, int n_in,
                              void* d_out, int out_size, void* d_ws, size_t ws_size,
                              hipStream_t stream)
{
    const float* x_in      = (const float*)d_in[0];
    const float* ln_proj_w = (const float*)d_in[1];
    const float* ln_proj_b = (const float*)d_in[2];
    const float* proj_p_w  = (const float*)d_in[3];
    const float* proj_p_b  = (const float*)d_in[4];
    const float* proj_d_w  = (const float*)d_in[5];
    const float* proj_d_b  = (const float*)d_in[6];
    const float* proj_a_w  = (const float*)d_in[7];
    const float* proj_a_b  = (const float*)d_in[8];
    const float* ln_attn_w = (const float*)d_in[9];
    const float* ln_attn_b = (const float*)d_in[10];
    const float* qkv_w     = (const float*)d_in[11];
    const float* qkv_b     = (const float*)d_in[12];
    const float* attn_o_w  = (const float*)d_in[13];
    const float* attn_o_b  = (const float*)d_in[14];
    const float* rpb       = (const float*)d_in[15];
    const float* dwcp1_w   = (const float*)d_in[16];
    const float* dwcp1_b   = (const float*)d_in[17];
    const float* dwcp2_w   = (const float*)d_in[18];
    const float* dwcp2_b   = (const float*)d_in[19];
    const float* pconv_w   = (const float*)d_in[20];
    const float* pconv_b   = (const float*)d_in[21];
    const float* ffn_p_w   = (const float*)d_in[22];
    const float* ffn_p_b   = (const float*)d_in[23];
    const float* ffn_d_w   = (const float*)d_in[24];
    const float* ffn_d_b   = (const float*)d_in[25];
    const float* ffn_a_w   = (const float*)d_in[26];
    const float* ffn_a_b   = (const float*)d_in[27];
    const float* ln_out_w  = (const float*)d_in[28];
    const float* ln_out_b  = (const float*)d_in[29];
    const float* conv_o_w  = (const float*)d_in[30];
    const float* conv_o_b  = (const float*)d_in[31];
    const float* plk       = (const float*)d_in[32];

    float* X  = (float*)d_out;
    float* ws = (float*)d_ws;

    // big path needs A(10.24M) + QKV(30.72M) + R2(2.56M) + tables ≈ 43.67M floats
    bool big = ws_size >= (size_t)43700000 * 4;

    float* A   = ws;                                  // 10.24M floats
    float* QKV = ws + 10240000;                       // 30.72M floats (big path; overlaps R1)
    float* R1  = ws + 10240000;                       // 20.48M floats
    float* R2  = big ? ws + 40960000 : ws + 30720000; // 2.56M floats
    float* LKT = R2 + 2560000;                        // 43264
    float* GM  = LKT + 43264;                         // 64
    float* DK  = GM + 64;                             // 576
    float* WT  = DK + 576;                            // 98304

    dim3 b256(256);
    dim3 gLN(157, 4);
    dim3 gT(13, 13, 4);

    prep_kernel<<<dim3(384), b256, 0, stream>>>(proj_p_w, attn_o_w, ffn_p_w, proj_a_w,
                                                ffn_a_w, pconv_w, conv_o_w, qkv_w, WT);
    geo_kernel<<<dim3(169), b256, 0, stream>>>(plk, LKT);

    // x = LN(x); x = conv_ffn(x) [proj]
    ln_kernel<<<gLN, b256, 0, stream>>>(x_in, ln_proj_w, ln_proj_b, A);
    conv1x1_kernel<<<dim3(40, 8, 4), b256, 0, stream>>>(A, WT + 0, proj_p_b, R1, 64, 128, 1, 0);
    dwproj_kernel<<<gT, b256, 0, stream>>>(R1, proj_d_w, proj_d_b, WT + 22528, proj_a_b, X, 128);

    // x = x + window_attention(LN(x))
    ln_kernel<<<gLN, b256, 0, stream>>>(X, ln_attn_w, ln_attn_b, A);
    if (big) {
        conv1x1_kernel<<<dim3(40, 12, 4), b256, 0, stream>>>(A, WT + 86016, qkv_b, QKV, 64, 192, 0, 0);
        winattn2_kernel<<<dim3(400, 8, 4), dim3(128), 0, stream>>>(QKV, rpb, A);
        conv1x1_kernel<<<dim3(40, 4, 4), b256, 0, stream>>>(A, WT + 8192, attn_o_b, X, 64, 64, 0, 1);
    } else {
        winattn_kernel<<<dim3(400, 8, 4), dim3(128), 0, stream>>>(A, qkv_w, qkv_b, rpb, R1);
        conv1x1_kernel<<<dim3(40, 4, 4), b256, 0, stream>>>(R1, WT + 8192, attn_o_b, X, 64, 64, 0, 1);
    }

    for (int i = 0; i < 2; ++i) {
        conv1x1_kernel<<<dim3(40, 5, 4), b256, 0, stream>>>(X, WT + 12288 + i * 5120, ffn_p_b + i * 80, R1, 64, 80, 1, 0);
        dwproj_kernel<<<gT, b256, 0, stream>>>(R1, ffn_d_w + i * 720, ffn_d_b + i * 80,
                                               WT + 30720 + i * 5120, ffn_a_b + i * 64, A, 80);
        gmean_kernel<<<dim3(64), b256, 0, stream>>>(A, GM);
        dynk_kernel<<<dim3(4), dim3(192), 0, stream>>>(GM, dwcp1_w + i * 128, dwcp1_b + i * 8,
                                                       dwcp2_w + i * 1152, dwcp2_b + i * 144, DK);
        lkconv_kernel<<<gT, b256, 0, stream>>>(A, LKT, DK, R2);
        pconv_add_kernel<<<dim3(40, 4, 4), b256, 0, stream>>>(R2, A, WT + 40960 + i * 4096, pconv_b + i * 64, X);
    }

    ln_kernel<<<gLN, b256, 0, stream>>>(X, ln_out_w, ln_out_b, A);
    conv3_skip_kernel<<<gT, b256, 0, stream>>>(A, WT + 49152, conv_o_b, x_in, X);
}